// Round 1
// baseline (148.905 us; speedup 1.0000x reference)
//
#include <hip/hip_runtime.h>

#define SEQ 8192
#define EMB 1024
#define DIM 64

typedef __attribute__((ext_vector_type(8))) short bf16x8;
typedef __attribute__((ext_vector_type(4))) float f32x4;

__device__ inline unsigned short f2bf(float f) {
    union { float f; unsigned u; } x; x.f = f;
    unsigned r = x.u + 0x7FFFu + ((x.u >> 16) & 1u);
    return (unsigned short)(r >> 16);
}

// ---------------- Projection: q = X@W + b (bf16 out), v stored transposed ----
__global__ __launch_bounds__(256) void proj_kernel(
    const float* __restrict__ x, const float* __restrict__ y, const float* __restrict__ z,
    const float* __restrict__ Wq, const float* __restrict__ bq,
    const float* __restrict__ Wk, const float* __restrict__ bk,
    const float* __restrict__ Wv, const float* __restrict__ bv,
    unsigned short* __restrict__ qkv)
{
    __shared__ unsigned short a_lds[64][72];   // X tile  [row][k]
    __shared__ unsigned short b_lds[64][72];   // W tile transposed [n][k]

    const int b   = blockIdx.x;        // 0..383
    const int mat = b >> 7;            // 0=q,1=k,2=v
    const int rb  = (b & 127) * 64;    // row base

    const float* X  = (mat == 0) ? x  : (mat == 1) ? y  : z;
    const float* W  = (mat == 0) ? Wq : (mat == 1) ? Wk : Wv;
    const float* Bv = (mat == 0) ? bq : (mat == 1) ? bk : bv;
    unsigned short* out = qkv + (size_t)mat * (SEQ * DIM);
    const bool transposed = (mat == 2);

    const int tid  = threadIdx.x;
    const int lane = tid & 63;
    const int w    = tid >> 6;
    const int c    = lane & 15;
    const int qq   = lane >> 4;

    f32x4 acc[4];
    #pragma unroll
    for (int nf = 0; nf < 4; ++nf) acc[nf] = (f32x4){0.f, 0.f, 0.f, 0.f};

    for (int k0 = 0; k0 < EMB; k0 += 64) {
        // stage X tile: 64 rows x 64 k, f32 -> bf16
        {
            const int kq  = (tid & 15) * 4;
            const int r0  = tid >> 4;          // 0..15
            #pragma unroll
            for (int p = 0; p < 4; ++p) {
                int row = r0 + p * 16;
                float4 v4 = *(const float4*)&X[(size_t)(rb + row) * EMB + k0 + kq];
                unsigned short* dst = &a_lds[row][kq];
                dst[0] = f2bf(v4.x); dst[1] = f2bf(v4.y);
                dst[2] = f2bf(v4.z); dst[3] = f2bf(v4.w);
            }
        }
        // stage W tile transposed: W[k][n] -> b_lds[n][k]
        {
            const int nq = (tid & 15) * 4;
            const int kk = tid >> 4;           // 0..15
            #pragma unroll
            for (int p = 0; p < 4; ++p) {
                int k = kk + p * 16;
                float4 v4 = *(const float4*)&W[(size_t)(k0 + k) * DIM + nq];
                b_lds[nq + 0][k] = f2bf(v4.x);
                b_lds[nq + 1][k] = f2bf(v4.y);
                b_lds[nq + 2][k] = f2bf(v4.z);
                b_lds[nq + 3][k] = f2bf(v4.w);
            }
        }
        __syncthreads();

        #pragma unroll
        for (int ks = 0; ks < 2; ++ks) {
            bf16x8 af = *(const bf16x8*)&a_lds[w * 16 + c][ks * 32 + qq * 8];
            #pragma unroll
            for (int nf = 0; nf < 4; ++nf) {
                bf16x8 bf = *(const bf16x8*)&b_lds[nf * 16 + c][ks * 32 + qq * 8];
                acc[nf] = __builtin_amdgcn_mfma_f32_16x16x32_bf16(af, bf, acc[nf], 0, 0, 0);
            }
        }
        __syncthreads();
    }

    // epilogue: + bias, -> bf16, store (v transposed)
    #pragma unroll
    for (int nf = 0; nf < 4; ++nf) {
        int col = nf * 16 + c;
        float bb = Bv[col];
        #pragma unroll
        for (int i = 0; i < 4; ++i) {
            int r = rb + w * 16 + qq * 4 + i;
            unsigned short val = f2bf(acc[nf][i] + bb);
            if (!transposed) out[(size_t)r * DIM + col] = val;
            else             out[(size_t)col * SEQ + r] = val;
        }
    }
}

// ---------------- Flash attention, causal, 16 Q-rows/block, 8-way kv split ---
__global__ __launch_bounds__(512) void attn_kernel(
    const unsigned short* __restrict__ qkv, float* __restrict__ out)
{
    const unsigned short* Q  = qkv;
    const unsigned short* K  = qkv + SEQ * DIM;
    const unsigned short* Vt = qkv + 2 * SEQ * DIM;   // [DIM][SEQ]

    __shared__ unsigned short P_lds[8][16][72];
    __shared__ float Oall[8][16][64];
    __shared__ float Ml[8][16][2];    // [w][row][0]=m, [1]=l

    const int tid  = threadIdx.x;
    const int lane = tid & 63;
    const int w    = tid >> 6;
    const int c    = lane & 15;
    const int qq   = lane >> 4;

    const int qt = gridDim.x - 1 - blockIdx.x;   // longest first
    const int m0 = qt * 16;

    const float scale = 0.011048543456f;   // 1/sqrt(8192)

    // Q fragments (row = c, k contiguous)
    bf16x8 qa0 = *(const bf16x8*)&Q[(size_t)(m0 + c) * DIM + qq * 8];
    bf16x8 qa1 = *(const bf16x8*)&Q[(size_t)(m0 + c) * DIM + 32 + qq * 8];

    f32x4 Oacc[4];
    #pragma unroll
    for (int df = 0; df < 4; ++df) Oacc[df] = (f32x4){0.f, 0.f, 0.f, 0.f};
    float m_i[4] = {-1e30f, -1e30f, -1e30f, -1e30f};
    float l_i[4] = {0.f, 0.f, 0.f, 0.f};

    const int nKv    = m0 + 16;
    const int nTiles = (nKv + 63) >> 6;
    const int t0 = (w * nTiles) >> 3;
    const int t1 = ((w + 1) * nTiles) >> 3;

    for (int t = t0; t < t1; ++t) {
        const int n0 = t * 64;
        // ---- S = Q @ K^T  (per nf: 16 kv rows) ----
        f32x4 s[4];
        #pragma unroll
        for (int nf = 0; nf < 4; ++nf) {
            const unsigned short* Kp = &K[(size_t)(n0 + nf * 16 + c) * DIM + qq * 8];
            bf16x8 kb0 = *(const bf16x8*)(Kp);
            bf16x8 kb1 = *(const bf16x8*)(Kp + 32);
            f32x4 z4 = (f32x4){0.f, 0.f, 0.f, 0.f};
            z4    = __builtin_amdgcn_mfma_f32_16x16x32_bf16(qa0, kb0, z4, 0, 0, 0);
            s[nf] = __builtin_amdgcn_mfma_f32_16x16x32_bf16(qa1, kb1, z4, 0, 0, 0);
        }
        // ---- scale + causal mask ----
        const bool edge = (n0 + 63 > m0);
        #pragma unroll
        for (int nf = 0; nf < 4; ++nf) {
            #pragma unroll
            for (int i = 0; i < 4; ++i) {
                float v = s[nf][i] * scale;
                if (edge) {
                    int col = n0 + nf * 16 + c;
                    int row = m0 + qq * 4 + i;
                    if (col > row) v = -1e30f;
                }
                s[nf][i] = v;
            }
        }
        // ---- row max (over 64 tile cols) ----
        float tm[4];
        #pragma unroll
        for (int i = 0; i < 4; ++i)
            tm[i] = fmaxf(fmaxf(s[0][i], s[1][i]), fmaxf(s[2][i], s[3][i]));
        #pragma unroll
        for (int msk = 1; msk < 16; msk <<= 1) {
            #pragma unroll
            for (int i = 0; i < 4; ++i) tm[i] = fmaxf(tm[i], __shfl_xor(tm[i], msk));
        }
        // ---- online-softmax update ----
        #pragma unroll
        for (int i = 0; i < 4; ++i) {
            float mn = fmaxf(m_i[i], tm[i]);
            float alpha = __expf(m_i[i] - mn);
            m_i[i] = mn;
            l_i[i] *= alpha;
            #pragma unroll
            for (int df = 0; df < 4; ++df) Oacc[df][i] *= alpha;
        }
        // ---- p = exp(s - m), row-sum, write P^ to LDS (bf16) ----
        float rs[4] = {0.f, 0.f, 0.f, 0.f};
        #pragma unroll
        for (int nf = 0; nf < 4; ++nf) {
            #pragma unroll
            for (int i = 0; i < 4; ++i) {
                float p = __expf(s[nf][i] - m_i[i]);
                rs[i] += p;
                P_lds[w][qq * 4 + i][nf * 16 + c] = f2bf(p);
            }
        }
        #pragma unroll
        for (int msk = 1; msk < 16; msk <<= 1) {
            #pragma unroll
            for (int i = 0; i < 4; ++i) rs[i] += __shfl_xor(rs[i], msk);
        }
        #pragma unroll
        for (int i = 0; i < 4; ++i) l_i[i] += rs[i];
        // ---- O += P @ V  (B-frag from Vt, contiguous) ----
        #pragma unroll
        for (int ks = 0; ks < 2; ++ks) {
            bf16x8 pa = *(const bf16x8*)&P_lds[w][c][ks * 32 + qq * 8];
            #pragma unroll
            for (int df = 0; df < 4; ++df) {
                bf16x8 vb = *(const bf16x8*)&Vt[(size_t)(df * 16 + c) * SEQ + n0 + ks * 32 + qq * 8];
                Oacc[df] = __builtin_amdgcn_mfma_f32_16x16x32_bf16(pa, vb, Oacc[df], 0, 0, 0);
            }
        }
    }

    // ---- write per-wave partials ----
    #pragma unroll
    for (int df = 0; df < 4; ++df)
        #pragma unroll
        for (int i = 0; i < 4; ++i)
            Oall[w][qq * 4 + i][df * 16 + c] = Oacc[df][i];
    if (c == 0) {
        #pragma unroll
        for (int i = 0; i < 4; ++i) {
            Ml[w][qq * 4 + i][0] = m_i[i];
            Ml[w][qq * 4 + i][1] = l_i[i];
        }
    }
    __syncthreads();

    // ---- combine 8 partial softmaxes ----
    #pragma unroll
    for (int e = tid; e < 16 * 64; e += 512) {
        int row = e >> 6, col = e & 63;
        float M = -1e30f;
        #pragma unroll
        for (int w2 = 0; w2 < 8; ++w2) M = fmaxf(M, Ml[w2][row][0]);
        float L = 0.f, val = 0.f;
        #pragma unroll
        for (int w2 = 0; w2 < 8; ++w2) {
            float sc = __expf(Ml[w2][row][0] - M);
            L   += Ml[w2][row][1] * sc;
            val += Oall[w2][row][col] * sc;
        }
        out[(size_t)(m0 + row) * DIM + col] = val / L;
    }
}

extern "C" void kernel_launch(void* const* d_in, const int* in_sizes, int n_in,
                              void* d_out, int out_size, void* d_ws, size_t ws_size,
                              hipStream_t stream) {
    const float* x  = (const float*)d_in[0];
    const float* y  = (const float*)d_in[1];
    const float* z  = (const float*)d_in[2];
    const float* Wq = (const float*)d_in[3];
    const float* bq = (const float*)d_in[4];
    const float* Wk = (const float*)d_in[5];
    const float* bk = (const float*)d_in[6];
    const float* Wv = (const float*)d_in[7];
    const float* bv = (const float*)d_in[8];

    unsigned short* qkv = (unsigned short*)d_ws;   // q | k | v^T, bf16, 3 MB
    float* out = (float*)d_out;

    hipLaunchKernelGGL(proj_kernel, dim3(384), dim3(256), 0, stream,
                       x, y, z, Wq, bq, Wk, bk, Wv, bv, qkv);
    hipLaunchKernelGGL(attn_kernel, dim3(512), dim3(512), 0, stream, qkv, out);
}

// Round 2
// 99.676 us; speedup vs baseline: 1.4939x; 1.4939x over previous
//
#include <hip/hip_runtime.h>

#define SEQ 8192
#define EMB 1024
#define DIM 64

typedef __attribute__((ext_vector_type(8))) short bf16x8;
typedef __attribute__((ext_vector_type(4))) float f32x4;
typedef __attribute__((ext_vector_type(16))) float f32x16;

#if __has_builtin(__builtin_amdgcn_exp2f)
#define EXP2 __builtin_amdgcn_exp2f
#else
#define EXP2 exp2f
#endif

// softmax scale folded with log2(e): (1/sqrt(8192)) * 1.4426950408889634
#define SCL 0.0159396779f

__device__ inline unsigned short f2bf(float f) {
    union { float f; unsigned u; } x; x.f = f;
    unsigned r = x.u + 0x7FFFu + ((x.u >> 16) & 1u);
    return (unsigned short)(r >> 16);
}

// ---------------------------------------------------------------------------
// ws layout (bytes):
//  qkv    @ 0         : q[8192][64] | k[8192][64] | vT[64][8192]   bf16 (3,145,728)
//  Wt     @ 3145728   : [3][64][1024] bf16 (393,216)
//  Opart  @ 3538944   : [1120][32][64] f32 (9,175,040)
//  MLpart @ 12713984  : [1120][32][2]  f32 (286,720)   -> total ~13.0 MB
// ---------------------------------------------------------------------------

// ---- W transpose + bf16 convert: Wt[mat][n][k] = bf16(W[k][n]) -------------
__global__ __launch_bounds__(256) void wt_kernel(
    const float* __restrict__ Wq, const float* __restrict__ Wk,
    const float* __restrict__ Wv, unsigned short* __restrict__ Wt)
{
    const int f0 = ((int)blockIdx.x * 256 + (int)threadIdx.x) * 4;  // flat [3][64][1024]
    const int mat = f0 >> 16;
    const int rem = f0 & 65535;
    const int n = rem >> 10;
    const int k = rem & 1023;
    const float* W = (mat == 0) ? Wq : (mat == 1) ? Wk : Wv;
    unsigned short r0 = f2bf(W[(size_t)(k + 0) * DIM + n]);
    unsigned short r1 = f2bf(W[(size_t)(k + 1) * DIM + n]);
    unsigned short r2 = f2bf(W[(size_t)(k + 2) * DIM + n]);
    unsigned short r3 = f2bf(W[(size_t)(k + 3) * DIM + n]);
    *(unsigned*)&Wt[f0 + 0] = (unsigned)r0 | ((unsigned)r1 << 16);
    *(unsigned*)&Wt[f0 + 2] = (unsigned)r2 | ((unsigned)r3 << 16);
}

__device__ inline bf16x8 cvt8(float4 a, float4 b) {
    bf16x8 r;
    r[0] = (short)f2bf(a.x); r[1] = (short)f2bf(a.y);
    r[2] = (short)f2bf(a.z); r[3] = (short)f2bf(a.w);
    r[4] = (short)f2bf(b.x); r[5] = (short)f2bf(b.y);
    r[6] = (short)f2bf(b.z); r[7] = (short)f2bf(b.w);
    return r;
}

// ---- Projection: no LDS, no barriers. 768 blocks x 128 thr -----------------
__global__ __launch_bounds__(128) void proj_kernel(
    const float* __restrict__ x, const float* __restrict__ y, const float* __restrict__ z,
    const float* __restrict__ bq, const float* __restrict__ bk, const float* __restrict__ bv,
    const unsigned short* __restrict__ Wt, unsigned short* __restrict__ qkv)
{
    const int bid = (int)blockIdx.x;
    const int mat = bid >> 8;                 // 0=q,1=k,2=v
    const int tid = (int)threadIdx.x;
    const int lane = tid & 63;
    const int w = tid >> 6;                   // 0..1
    const int c = lane & 15;
    const int qq = lane >> 4;
    const int rb = (bid & 255) * 32 + w * 16;

    const float* X  = (mat == 0) ? x  : (mat == 1) ? y  : z;
    const float* Bv = (mat == 0) ? bq : (mat == 1) ? bk : bv;
    const unsigned short* Wm = Wt + (size_t)mat * (DIM * EMB);
    unsigned short* outp = qkv + (size_t)mat * (SEQ * DIM);

    f32x4 acc[4];
    #pragma unroll
    for (int nf = 0; nf < 4; ++nf) acc[nf] = (f32x4){0.f, 0.f, 0.f, 0.f};

    const float* Xr = X + (size_t)(rb + c) * EMB + qq * 8;
    float4 xa = *(const float4*)(Xr + 0);
    float4 xb = *(const float4*)(Xr + 4);
    for (int k0 = 0; k0 < EMB; k0 += 32) {
        float4 na = {0,0,0,0}, nb = {0,0,0,0};
        if (k0 + 32 < EMB) {
            na = *(const float4*)(Xr + k0 + 32);
            nb = *(const float4*)(Xr + k0 + 36);
        }
        bf16x8 af = cvt8(xa, xb);
        #pragma unroll
        for (int nf = 0; nf < 4; ++nf) {
            bf16x8 bfr = *(const bf16x8*)&Wm[(size_t)(nf * 16 + c) * EMB + k0 + qq * 8];
            acc[nf] = __builtin_amdgcn_mfma_f32_16x16x32_bf16(af, bfr, acc[nf], 0, 0, 0);
        }
        xa = na; xb = nb;
    }

    if (mat != 2) {
        #pragma unroll
        for (int nf = 0; nf < 4; ++nf) {
            const int col = nf * 16 + c;
            const float bb = Bv[col];
            #pragma unroll
            for (int i = 0; i < 4; ++i) {
                const int row = rb + qq * 4 + i;
                outp[(size_t)row * DIM + col] = f2bf(acc[nf][i] + bb);
            }
        }
    } else {   // store V transposed: vT[d][row]
        #pragma unroll
        for (int nf = 0; nf < 4; ++nf) {
            const int col = nf * 16 + c;
            const float bb = Bv[col];
            #pragma unroll
            for (int i = 0; i < 4; ++i) {
                const int row = rb + qq * 4 + i;
                outp[(size_t)col * SEQ + row] = f2bf(acc[nf][i] + bb);
            }
        }
    }
}

// ---- Flash attention: swapped-operand 32x32, in-register softmax -----------
// 1152 blocks x 256 thr (4 waves). Unit = (qtile, 32-tile KV chunk).
__global__ __launch_bounds__(256, 3) void attn_kernel(
    const unsigned short* __restrict__ qkv, float* __restrict__ out,
    float* __restrict__ Opart, float* __restrict__ MLpart)
{
    const unsigned short* Q  = qkv;
    const unsigned short* K  = qkv + SEQ * DIM;
    const unsigned short* Vt = qkv + 2 * SEQ * DIM;   // [64][8192]

    __shared__ float Oall[4][32][68];
    __shared__ float Ml[4][32][2];
    __shared__ float sScl[4][32];
    __shared__ float sM[32];
    __shared__ float sL[32];

    // unit id, longest-first
    const int u = 1151 - (int)blockIdx.x;
    int g;
    if (u < 32) g = 0; else if (u < 96) g = 1; else if (u < 192) g = 2;
    else if (u < 320) g = 3; else if (u < 480) g = 4; else if (u < 672) g = 5;
    else if (u < 896) g = 6; else g = 7;
    const int o_  = u - 16 * g * (g + 1);
    const int qt  = 32 * g + o_ / (g + 1);
    const int cid = o_ - (o_ / (g + 1)) * (g + 1);

    const int m0 = qt * 32;
    const int tid = (int)threadIdx.x;
    const int lane = tid & 63;
    const int w = tid >> 6;        // 0..3
    const int col = lane & 31;     // q row within tile
    const int hi = lane >> 5;

    // Q fragments (B-operand): lane holds Q[m0+col][ks*16 + hi*8 + j]
    bf16x8 qf[4];
    {
        const unsigned short* Qr = Q + (size_t)(m0 + col) * DIM + hi * 8;
        #pragma unroll
        for (int ks = 0; ks < 4; ++ks) qf[ks] = *(const bf16x8*)(Qr + ks * 16);
    }

    f32x16 o0, o1;
    #pragma unroll
    for (int r = 0; r < 16; ++r) { o0[r] = 0.f; o1[r] = 0.f; }
    float m_i = -1e30f, l_i = 0.f;

    const int nT = qt + 1;
    const int tb = cid * 32;
    const int te = (tb + 32 < nT) ? (tb + 32) : nT;
    const int nC = te - tb;
    const int w0 = tb + ((nC * w) >> 2);
    const int w1 = tb + ((nC * (w + 1)) >> 2);

    for (int t = w0; t < w1; ++t) {
        const int n0 = t * 32;
        // S^T = K . Q^T : lane holds S^T[kv=crow(r,hi)][q=col]
        const unsigned short* Kr = K + (size_t)(n0 + col) * DIM + hi * 8;
        f32x16 s;
        #pragma unroll
        for (int r = 0; r < 16; ++r) s[r] = 0.f;
        #pragma unroll
        for (int ks = 0; ks < 4; ++ks) {
            bf16x8 kf = *(const bf16x8*)(Kr + ks * 16);
            s = __builtin_amdgcn_mfma_f32_32x32x16_bf16(kf, qf[ks], s, 0, 0, 0);
        }
        float p[16];
        #pragma unroll
        for (int r = 0; r < 16; ++r) p[r] = s[r] * SCL;
        if (t == qt) {   // diagonal tile: mask kv > q  (n0 == m0 here)
            #pragma unroll
            for (int r = 0; r < 16; ++r) {
                const int kvr = (r & 3) + 8 * (r >> 2) + 4 * hi;
                if (kvr > col) p[r] = -1e30f;
            }
        }
        // row (over kv) max: 16 regs + partner half
        float tm = p[0];
        #pragma unroll
        for (int r = 1; r < 16; ++r) tm = fmaxf(tm, p[r]);
        tm = fmaxf(tm, __shfl_xor(tm, 32));
        const float mn = fmaxf(m_i, tm);
        const float alpha = EXP2(m_i - mn);
        m_i = mn;
        l_i *= alpha;
        #pragma unroll
        for (int r = 0; r < 16; ++r) { o0[r] *= alpha; o1[r] *= alpha; }
        float rs = 0.f;
        #pragma unroll
        for (int r = 0; r < 16; ++r) { p[r] = EXP2(p[r] - m_i); rs += p[r]; }
        rs += __shfl_xor(rs, 32);
        l_i += rs;

        // pack P -> bf16 words; permlane32_swap builds P^T B-fragments
        unsigned pw[8];
        #pragma unroll
        for (int i = 0; i < 8; ++i)
            pw[i] = (unsigned)f2bf(p[2 * i]) | ((unsigned)f2bf(p[2 * i + 1]) << 16);
        asm volatile("v_permlane32_swap_b32 %0, %1" : "+v"(pw[0]), "+v"(pw[2]));
        asm volatile("v_permlane32_swap_b32 %0, %1" : "+v"(pw[1]), "+v"(pw[3]));
        asm volatile("v_permlane32_swap_b32 %0, %1" : "+v"(pw[4]), "+v"(pw[6]));
        asm volatile("v_permlane32_swap_b32 %0, %1" : "+v"(pw[5]), "+v"(pw[7]));
        union { unsigned uu[4]; bf16x8 v; } pa0, pa1;
        pa0.uu[0] = pw[0]; pa0.uu[1] = pw[1]; pa0.uu[2] = pw[2]; pa0.uu[3] = pw[3];
        pa1.uu[0] = pw[4]; pa1.uu[1] = pw[5]; pa1.uu[2] = pw[6]; pa1.uu[3] = pw[7];

        // O^T += V^T . P^T  (A = vT rows = d, contiguous loads)
        const unsigned short* Vr0 = Vt + (size_t)col * SEQ + n0 + hi * 8;
        const unsigned short* Vr1 = Vt + (size_t)(32 + col) * SEQ + n0 + hi * 8;
        bf16x8 v00 = *(const bf16x8*)(Vr0);
        bf16x8 v01 = *(const bf16x8*)(Vr0 + 16);
        bf16x8 v10 = *(const bf16x8*)(Vr1);
        bf16x8 v11 = *(const bf16x8*)(Vr1 + 16);
        o0 = __builtin_amdgcn_mfma_f32_32x32x16_bf16(v00, pa0.v, o0, 0, 0, 0);
        o0 = __builtin_amdgcn_mfma_f32_32x32x16_bf16(v01, pa1.v, o0, 0, 0, 0);
        o1 = __builtin_amdgcn_mfma_f32_32x32x16_bf16(v10, pa0.v, o1, 0, 0, 0);
        o1 = __builtin_amdgcn_mfma_f32_32x32x16_bf16(v11, pa1.v, o1, 0, 0, 0);
    }

    // per-wave partial -> LDS (O^T: lane col = q, regs = d)
    #pragma unroll
    for (int r = 0; r < 16; ++r) {
        const int d = (r & 3) + 8 * (r >> 2) + 4 * hi;
        Oall[w][col][d]      = o0[r];
        Oall[w][col][32 + d] = o1[r];
    }
    if (hi == 0) { Ml[w][col][0] = m_i; Ml[w][col][1] = l_i; }
    __syncthreads();

    if (tid < 32) {
        float M = Ml[0][tid][0];
        #pragma unroll
        for (int w2 = 1; w2 < 4; ++w2) M = fmaxf(M, Ml[w2][tid][0]);
        sM[tid] = M;
    }
    __syncthreads();
    if (tid < 128) {
        const int w2 = tid >> 5, r = tid & 31;
        sScl[w2][r] = EXP2(Ml[w2][r][0] - sM[r]);
    }
    __syncthreads();
    if (tid < 32) {
        float L = 0.f;
        #pragma unroll
        for (int w2 = 0; w2 < 4; ++w2) L += Ml[w2][tid][1] * sScl[w2][tid];
        sL[tid] = L;
    }
    __syncthreads();

    const int r = tid >> 3;
    const int c0 = (tid & 7) * 8;
    f32x4 a0 = (f32x4){0.f, 0.f, 0.f, 0.f};
    f32x4 a1 = (f32x4){0.f, 0.f, 0.f, 0.f};
    #pragma unroll
    for (int w2 = 0; w2 < 4; ++w2) {
        const float sc = sScl[w2][r];
        const float* Orow = &Oall[w2][r][c0];
        a0 += (*(const f32x4*)(Orow)) * sc;
        a1 += (*(const f32x4*)(Orow + 4)) * sc;
    }
    if (qt < 32) {   // single chunk: write final output
        const float inv = 1.f / sL[r];
        float* op = out + (size_t)(m0 + r) * DIM + c0;
        *(f32x4*)(op)     = a0 * inv;
        *(f32x4*)(op + 4) = a1 * inv;
    } else {         // write partial for fixup
        const int pb = 16 * (g - 1) * (g + 2) + (qt - 32 * g) * (g + 1) + cid;
        float* op = Opart + (size_t)pb * 2048 + r * 64 + c0;
        *(f32x4*)(op)     = a0;
        *(f32x4*)(op + 4) = a1;
        if (tid < 32) {
            MLpart[(size_t)pb * 64 + tid * 2]     = sM[tid];
            MLpart[(size_t)pb * 64 + tid * 2 + 1] = sL[tid];
        }
    }
}

// ---- Fixup: merge chunk partials for qt >= 32. 224 blocks x 256 ------------
__global__ __launch_bounds__(256) void fixup_kernel(
    const float* __restrict__ Opart, const float* __restrict__ MLpart,
    float* __restrict__ out)
{
    __shared__ float sScl[8][32];
    __shared__ float sInvL[32];

    const int qt = 32 + (int)blockIdx.x;
    const int g  = qt >> 5;
    const int nc = g + 1;
    const int pb = 16 * (g - 1) * (g + 2) + (qt - 32 * g) * nc;
    const int tid = (int)threadIdx.x;

    if (tid < 32) {
        float M = -1e30f;
        for (int c2 = 0; c2 < nc; ++c2)
            M = fmaxf(M, MLpart[(size_t)(pb + c2) * 64 + tid * 2]);
        float L = 0.f;
        for (int c2 = 0; c2 < nc; ++c2) {
            const float sc = EXP2(MLpart[(size_t)(pb + c2) * 64 + tid * 2] - M);
            sScl[c2][tid] = sc;
            L += MLpart[(size_t)(pb + c2) * 64 + tid * 2 + 1] * sc;
        }
        sInvL[tid] = 1.f / L;
    }
    __syncthreads();

    const int r = tid >> 3;
    const int c0 = (tid & 7) * 8;
    f32x4 a0 = (f32x4){0.f, 0.f, 0.f, 0.f};
    f32x4 a1 = (f32x4){0.f, 0.f, 0.f, 0.f};
    for (int c2 = 0; c2 < nc; ++c2) {
        const float sc = sScl[c2][r];
        const float* Op = Opart + (size_t)(pb + c2) * 2048 + r * 64 + c0;
        a0 += (*(const f32x4*)(Op)) * sc;
        a1 += (*(const f32x4*)(Op + 4)) * sc;
    }
    const float inv = sInvL[r];
    float* op = out + (size_t)(qt * 32 + r) * DIM + c0;
    *(f32x4*)(op)     = a0 * inv;
    *(f32x4*)(op + 4) = a1 * inv;
}

extern "C" void kernel_launch(void* const* d_in, const int* in_sizes, int n_in,
                              void* d_out, int out_size, void* d_ws, size_t ws_size,
                              hipStream_t stream) {
    const float* x  = (const float*)d_in[0];
    const float* y  = (const float*)d_in[1];
    const float* z  = (const float*)d_in[2];
    const float* Wq = (const float*)d_in[3];
    const float* bq = (const float*)d_in[4];
    const float* Wk = (const float*)d_in[5];
    const float* bk = (const float*)d_in[6];
    const float* Wv = (const float*)d_in[7];
    const float* bv = (const float*)d_in[8];

    unsigned short* qkv = (unsigned short*)d_ws;
    unsigned short* Wt  = (unsigned short*)((char*)d_ws + 3145728);
    float* Opart        = (float*)((char*)d_ws + 3538944);
    float* MLpart       = (float*)((char*)d_ws + 12713984);
    float* out          = (float*)d_out;

    hipLaunchKernelGGL(wt_kernel,    dim3(192),  dim3(256), 0, stream, Wq, Wk, Wv, Wt);
    hipLaunchKernelGGL(proj_kernel,  dim3(768),  dim3(128), 0, stream, x, y, z, bq, bk, bv, Wt, qkv);
    hipLaunchKernelGGL(attn_kernel,  dim3(1152), dim3(256), 0, stream, qkv, out, Opart, MLpart);
    hipLaunchKernelGGL(fixup_kernel, dim3(224),  dim3(256), 0, stream, Opart, MLpart, out);
}

// Round 3
// 91.094 us; speedup vs baseline: 1.6346x; 1.0942x over previous
//
#include <hip/hip_runtime.h>

#define SEQ 8192
#define EMB 1024
#define DIM 64

typedef __attribute__((ext_vector_type(8))) short bf16x8;
typedef __attribute__((ext_vector_type(4))) float f32x4;
typedef __attribute__((ext_vector_type(16))) float f32x16;

#if __has_builtin(__builtin_amdgcn_exp2f)
#define EXP2 __builtin_amdgcn_exp2f
#else
#define EXP2 exp2f
#endif

// softmax scale folded with log2(e): (1/sqrt(8192)) * 1.4426950408889634
#define SCL 0.0159396779f

__device__ inline unsigned short f2bf(float f) {
    union { float f; unsigned u; } x; x.f = f;
    unsigned r = x.u + 0x7FFFu + ((x.u >> 16) & 1u);
    return (unsigned short)(r >> 16);
}

__device__ inline unsigned cvtpk(float lo, float hi) {
    unsigned r;
    asm("v_cvt_pk_bf16_f32 %0, %1, %2" : "=v"(r) : "v"(lo), "v"(hi));
    return r;
}

// ---------------------------------------------------------------------------
// ws layout (bytes):
//  qkv    @ 0         : q[8192][64] | k[8192][64] | vT[64][8192]   bf16 (3,145,728)
//  Wt     @ 3145728   : [3][64][1024] bf16, k-PERMUTED layout (393,216)
//  Opart  @ 3538944   : [1120][32][64] f32 (9,175,040)
//  MLpart @ 12713984  : [1120][32][2]  f32 (286,720)
// ---------------------------------------------------------------------------

// ---- W transpose + bf16 + k-permute --------------------------------------
// Wt[mat][n][w32 + qq*8 + j] = bf16(W[w32 + qq*4 + (j&3) + 16*(j>>2)][n])
// so that proj's coalesced float4 X loads (cols qq*4 and 16+qq*4) pair with
// the matching W elements in the same MFMA k-slot.
__global__ __launch_bounds__(256) void wt_kernel(
    const float* __restrict__ Wq, const float* __restrict__ Wk,
    const float* __restrict__ Wv, unsigned short* __restrict__ Wt)
{
    const int f = (int)blockIdx.x * 256 + (int)threadIdx.x;  // 49152 threads
    const int n    = f & 63;
    const int rest = f >> 6;
    const int mat  = rest >> 8;
    const int kp   = (rest & 255) * 4;      // k' base (multiple of 4)
    const float* W = (mat == 0) ? Wq : (mat == 1) ? Wk : Wv;
    const int w32 = kp & ~31;
    const int qq  = (kp >> 3) & 3;
    const int jg  = (kp >> 2) & 1;
    const int kb  = w32 + qq * 4 + jg * 16;
    unsigned short r0 = f2bf(W[(size_t)(kb + 0) * DIM + n]);
    unsigned short r1 = f2bf(W[(size_t)(kb + 1) * DIM + n]);
    unsigned short r2 = f2bf(W[(size_t)(kb + 2) * DIM + n]);
    unsigned short r3 = f2bf(W[(size_t)(kb + 3) * DIM + n]);
    unsigned* dst = (unsigned*)&Wt[(size_t)mat * 65536 + (size_t)n * 1024 + kp];
    dst[0] = (unsigned)r0 | ((unsigned)r1 << 16);
    dst[1] = (unsigned)r2 | ((unsigned)r3 << 16);
}

__device__ inline bf16x8 cvt8(float4 a, float4 b) {
    bf16x8 r;
    r[0] = (short)f2bf(a.x); r[1] = (short)f2bf(a.y);
    r[2] = (short)f2bf(a.z); r[3] = (short)f2bf(a.w);
    r[4] = (short)f2bf(b.x); r[5] = (short)f2bf(b.y);
    r[6] = (short)f2bf(b.z); r[7] = (short)f2bf(b.w);
    return r;
}

// ---- Projection: no LDS, 4-deep load pipeline. 768 blocks x 128 thr --------
__global__ __launch_bounds__(128) void proj_kernel(
    const float* __restrict__ x, const float* __restrict__ y, const float* __restrict__ z,
    const float* __restrict__ bq, const float* __restrict__ bk, const float* __restrict__ bv,
    const unsigned short* __restrict__ Wt, unsigned short* __restrict__ qkv)
{
    const int bid = (int)blockIdx.x;
    const int mat = bid >> 8;                 // 0=q,1=k,2=v
    const int tid = (int)threadIdx.x;
    const int lane = tid & 63;
    const int w = tid >> 6;                   // 0..1
    const int c = lane & 15;
    const int qq = lane >> 4;
    const int rb = (bid & 255) * 32 + w * 16;

    const float* X  = (mat == 0) ? x  : (mat == 1) ? y  : z;
    const float* Bv = (mat == 0) ? bq : (mat == 1) ? bk : bv;
    const unsigned short* Wm = Wt + (size_t)mat * (DIM * EMB);
    unsigned short* outp = qkv + (size_t)mat * (SEQ * DIM);

    f32x4 acc[4];
    #pragma unroll
    for (int nf = 0; nf < 4; ++nf) acc[nf] = (f32x4){0.f, 0.f, 0.f, 0.f};

    const float* Xr = X + (size_t)(rb + c) * EMB;
    const int cb = qq * 4;

    float4 A[4], B[4];
    #pragma unroll
    for (int i = 0; i < 4; ++i) {
        A[i] = *(const float4*)(Xr + i * 32 + cb);
        B[i] = *(const float4*)(Xr + i * 32 + 16 + cb);
    }

    #pragma unroll
    for (int so = 0; so < 8; ++so) {
        #pragma unroll
        for (int u2 = 0; u2 < 4; ++u2) {
            const int s = so * 4 + u2;
            bf16x8 af = cvt8(A[u2], B[u2]);
            if (s + 4 < 32) {
                A[u2] = *(const float4*)(Xr + (s + 4) * 32 + cb);
                B[u2] = *(const float4*)(Xr + (s + 4) * 32 + 16 + cb);
            }
            #pragma unroll
            for (int nf = 0; nf < 4; ++nf) {
                bf16x8 bfr = *(const bf16x8*)&Wm[(size_t)(nf * 16 + c) * EMB + s * 32 + qq * 8];
                acc[nf] = __builtin_amdgcn_mfma_f32_16x16x32_bf16(af, bfr, acc[nf], 0, 0, 0);
            }
        }
    }

    if (mat != 2) {
        #pragma unroll
        for (int nf = 0; nf < 4; ++nf) {
            const int col = nf * 16 + c;
            const float bb = Bv[col];
            #pragma unroll
            for (int i = 0; i < 4; ++i) {
                const int row = rb + qq * 4 + i;
                outp[(size_t)row * DIM + col] = f2bf(acc[nf][i] + bb);
            }
        }
    } else {   // store V transposed: vT[d][row]
        #pragma unroll
        for (int nf = 0; nf < 4; ++nf) {
            const int col = nf * 16 + c;
            const float bb = Bv[col];
            #pragma unroll
            for (int i = 0; i < 4; ++i) {
                const int row = rb + qq * 4 + i;
                outp[(size_t)col * SEQ + row] = f2bf(acc[nf][i] + bb);
            }
        }
    }
}

// ---- Flash attention: swapped-operand 32x32, KVBLK=64 pairs, defer-max -----
// 1152 blocks x 256 thr (4 waves). Unit = (qtile, 32-tile KV chunk).
__global__ __launch_bounds__(256, 3) void attn_kernel(
    const unsigned short* __restrict__ qkv, float* __restrict__ out,
    float* __restrict__ Opart, float* __restrict__ MLpart)
{
    const unsigned short* Q  = qkv;
    const unsigned short* K  = qkv + SEQ * DIM;
    const unsigned short* Vt = qkv + 2 * SEQ * DIM;   // [64][8192]

    __shared__ float Oall[4][32][68];
    __shared__ float Ml[4][32][2];
    __shared__ float sScl[4][32];
    __shared__ float sM[32];
    __shared__ float sL[32];

    // unit id, longest-first
    const int u = 1151 - (int)blockIdx.x;
    int g;
    if (u < 32) g = 0; else if (u < 96) g = 1; else if (u < 192) g = 2;
    else if (u < 320) g = 3; else if (u < 480) g = 4; else if (u < 672) g = 5;
    else if (u < 896) g = 6; else g = 7;
    const int o_  = u - 16 * g * (g + 1);
    const int qt  = 32 * g + o_ / (g + 1);
    const int cid = o_ - (o_ / (g + 1)) * (g + 1);

    const int m0 = qt * 32;
    const int tid = (int)threadIdx.x;
    const int lane = tid & 63;
    const int w = tid >> 6;        // 0..3
    const int col = lane & 31;     // q row within tile
    const int hi = lane >> 5;

    // Q fragments (B-operand)
    bf16x8 qf[4];
    {
        const unsigned short* Qr = Q + (size_t)(m0 + col) * DIM + hi * 8;
        #pragma unroll
        for (int ks = 0; ks < 4; ++ks) qf[ks] = *(const bf16x8*)(Qr + ks * 16);
    }

    f32x16 o0, o1;
    #pragma unroll
    for (int r = 0; r < 16; ++r) { o0[r] = 0.f; o1[r] = 0.f; }
    float m_i = -1e30f, l_i = 0.f;

    const int nT = qt + 1;
    const int tb = cid * 32;
    const int te = (tb + 32 < nT) ? (tb + 32) : nT;
    const int nC = te - tb;
    const int w0 = tb + ((nC * w) >> 2);
    const int w1 = tb + ((nC * (w + 1)) >> 2);
    const int nW = w1 - w0;
    const int nP = nW >> 1;

    for (int pi = 0; pi < nP; ++pi) {
        const int t = w0 + 2 * pi;
        const int n0 = t * 32;
        // ---- load K (both tiles) and V (both tiles) up-front ----
        const unsigned short* KrA = K + (size_t)(n0 + col) * DIM + hi * 8;
        bf16x8 kA[4], kB[4];
        #pragma unroll
        for (int ks = 0; ks < 4; ++ks) kA[ks] = *(const bf16x8*)(KrA + ks * 16);
        #pragma unroll
        for (int ks = 0; ks < 4; ++ks) kB[ks] = *(const bf16x8*)(KrA + 32 * DIM + ks * 16);
        const unsigned short* Vr0 = Vt + (size_t)col * SEQ + n0 + hi * 8;
        const unsigned short* Vr1 = Vr0 + 32 * SEQ;
        bf16x8 va[4], vb[4];
        #pragma unroll
        for (int i = 0; i < 4; ++i) va[i] = *(const bf16x8*)(Vr0 + i * 16);
        #pragma unroll
        for (int i = 0; i < 4; ++i) vb[i] = *(const bf16x8*)(Vr1 + i * 16);

        // ---- dual QK chains ----
        f32x16 sa, sb;
        #pragma unroll
        for (int r = 0; r < 16; ++r) { sa[r] = 0.f; sb[r] = 0.f; }
        __builtin_amdgcn_s_setprio(1);
        #pragma unroll
        for (int ks = 0; ks < 4; ++ks) {
            sa = __builtin_amdgcn_mfma_f32_32x32x16_bf16(kA[ks], qf[ks], sa, 0, 0, 0);
            sb = __builtin_amdgcn_mfma_f32_32x32x16_bf16(kB[ks], qf[ks], sb, 0, 0, 0);
        }
        __builtin_amdgcn_s_setprio(0);

        float p0[16], p1[16];
        #pragma unroll
        for (int r = 0; r < 16; ++r) { p0[r] = sa[r] * SCL; p1[r] = sb[r] * SCL; }
        if (t + 1 == qt) {   // diagonal can only be the second tile of a pair
            #pragma unroll
            for (int r = 0; r < 16; ++r) {
                const int kvr = (r & 3) + 8 * (r >> 2) + 4 * hi;
                if (kvr > col) p1[r] = -1e30f;
            }
        }
        // ---- row max over 64 kv ----
        float tm = fmaxf(p0[0], p1[0]);
        #pragma unroll
        for (int r = 1; r < 16; ++r) tm = fmaxf(tm, fmaxf(p0[r], p1[r]));
        tm = fmaxf(tm, __shfl_xor(tm, 32));
        // ---- defer-max: skip rescale when max didn't grow past margin ----
        if (!__all(tm <= m_i + 2.0f)) {
            const float mn = fmaxf(m_i, tm);
            const float alpha = EXP2(m_i - mn);
            m_i = mn;
            l_i *= alpha;
            #pragma unroll
            for (int r = 0; r < 16; ++r) { o0[r] *= alpha; o1[r] *= alpha; }
        }
        float rs = 0.f;
        #pragma unroll
        for (int r = 0; r < 16; ++r) { p0[r] = EXP2(p0[r] - m_i); rs += p0[r]; }
        #pragma unroll
        for (int r = 0; r < 16; ++r) { p1[r] = EXP2(p1[r] - m_i); rs += p1[r]; }
        rs += __shfl_xor(rs, 32);
        l_i += rs;

        // ---- pack P -> bf16 (cvt_pk) + permlane32_swap -> B-fragments ----
        unsigned pwA[8], pwB[8];
        #pragma unroll
        for (int i = 0; i < 8; ++i) pwA[i] = cvtpk(p0[2 * i], p0[2 * i + 1]);
        #pragma unroll
        for (int i = 0; i < 8; ++i) pwB[i] = cvtpk(p1[2 * i], p1[2 * i + 1]);
        asm volatile("v_permlane32_swap_b32 %0, %1" : "+v"(pwA[0]), "+v"(pwA[2]));
        asm volatile("v_permlane32_swap_b32 %0, %1" : "+v"(pwA[1]), "+v"(pwA[3]));
        asm volatile("v_permlane32_swap_b32 %0, %1" : "+v"(pwA[4]), "+v"(pwA[6]));
        asm volatile("v_permlane32_swap_b32 %0, %1" : "+v"(pwA[5]), "+v"(pwA[7]));
        asm volatile("v_permlane32_swap_b32 %0, %1" : "+v"(pwB[0]), "+v"(pwB[2]));
        asm volatile("v_permlane32_swap_b32 %0, %1" : "+v"(pwB[1]), "+v"(pwB[3]));
        asm volatile("v_permlane32_swap_b32 %0, %1" : "+v"(pwB[4]), "+v"(pwB[6]));
        asm volatile("v_permlane32_swap_b32 %0, %1" : "+v"(pwB[5]), "+v"(pwB[7]));
        union { unsigned uu[4]; bf16x8 v; } pa0, pa1, pb0, pb1;
        pa0.uu[0] = pwA[0]; pa0.uu[1] = pwA[1]; pa0.uu[2] = pwA[2]; pa0.uu[3] = pwA[3];
        pa1.uu[0] = pwA[4]; pa1.uu[1] = pwA[5]; pa1.uu[2] = pwA[6]; pa1.uu[3] = pwA[7];
        pb0.uu[0] = pwB[0]; pb0.uu[1] = pwB[1]; pb0.uu[2] = pwB[2]; pb0.uu[3] = pwB[3];
        pb1.uu[0] = pwB[4]; pb1.uu[1] = pwB[5]; pb1.uu[2] = pwB[6]; pb1.uu[3] = pwB[7];

        // ---- O^T += V^T . P^T ----
        __builtin_amdgcn_s_setprio(1);
        o0 = __builtin_amdgcn_mfma_f32_32x32x16_bf16(va[0], pa0.v, o0, 0, 0, 0);
        o1 = __builtin_amdgcn_mfma_f32_32x32x16_bf16(vb[0], pa0.v, o1, 0, 0, 0);
        o0 = __builtin_amdgcn_mfma_f32_32x32x16_bf16(va[1], pa1.v, o0, 0, 0, 0);
        o1 = __builtin_amdgcn_mfma_f32_32x32x16_bf16(vb[1], pa1.v, o1, 0, 0, 0);
        o0 = __builtin_amdgcn_mfma_f32_32x32x16_bf16(va[2], pb0.v, o0, 0, 0, 0);
        o1 = __builtin_amdgcn_mfma_f32_32x32x16_bf16(vb[2], pb0.v, o1, 0, 0, 0);
        o0 = __builtin_amdgcn_mfma_f32_32x32x16_bf16(va[3], pb1.v, o0, 0, 0, 0);
        o1 = __builtin_amdgcn_mfma_f32_32x32x16_bf16(vb[3], pb1.v, o1, 0, 0, 0);
        __builtin_amdgcn_s_setprio(0);
    }

    if (nW & 1) {   // tail single tile
        const int t = w1 - 1;
        const int n0 = t * 32;
        const unsigned short* Kr = K + (size_t)(n0 + col) * DIM + hi * 8;
        bf16x8 kA[4];
        #pragma unroll
        for (int ks = 0; ks < 4; ++ks) kA[ks] = *(const bf16x8*)(Kr + ks * 16);
        const unsigned short* Vr0 = Vt + (size_t)col * SEQ + n0 + hi * 8;
        const unsigned short* Vr1 = Vr0 + 32 * SEQ;
        bf16x8 va0 = *(const bf16x8*)(Vr0);
        bf16x8 va1 = *(const bf16x8*)(Vr0 + 16);
        bf16x8 vb0 = *(const bf16x8*)(Vr1);
        bf16x8 vb1 = *(const bf16x8*)(Vr1 + 16);

        f32x16 sa;
        #pragma unroll
        for (int r = 0; r < 16; ++r) sa[r] = 0.f;
        __builtin_amdgcn_s_setprio(1);
        #pragma unroll
        for (int ks = 0; ks < 4; ++ks)
            sa = __builtin_amdgcn_mfma_f32_32x32x16_bf16(kA[ks], qf[ks], sa, 0, 0, 0);
        __builtin_amdgcn_s_setprio(0);

        float p0[16];
        #pragma unroll
        for (int r = 0; r < 16; ++r) p0[r] = sa[r] * SCL;
        if (t == qt) {
            #pragma unroll
            for (int r = 0; r < 16; ++r) {
                const int kvr = (r & 3) + 8 * (r >> 2) + 4 * hi;
                if (kvr > col) p0[r] = -1e30f;
            }
        }
        float tm = p0[0];
        #pragma unroll
        for (int r = 1; r < 16; ++r) tm = fmaxf(tm, p0[r]);
        tm = fmaxf(tm, __shfl_xor(tm, 32));
        if (!__all(tm <= m_i + 2.0f)) {
            const float mn = fmaxf(m_i, tm);
            const float alpha = EXP2(m_i - mn);
            m_i = mn;
            l_i *= alpha;
            #pragma unroll
            for (int r = 0; r < 16; ++r) { o0[r] *= alpha; o1[r] *= alpha; }
        }
        float rs = 0.f;
        #pragma unroll
        for (int r = 0; r < 16; ++r) { p0[r] = EXP2(p0[r] - m_i); rs += p0[r]; }
        rs += __shfl_xor(rs, 32);
        l_i += rs;

        unsigned pwA[8];
        #pragma unroll
        for (int i = 0; i < 8; ++i) pwA[i] = cvtpk(p0[2 * i], p0[2 * i + 1]);
        asm volatile("v_permlane32_swap_b32 %0, %1" : "+v"(pwA[0]), "+v"(pwA[2]));
        asm volatile("v_permlane32_swap_b32 %0, %1" : "+v"(pwA[1]), "+v"(pwA[3]));
        asm volatile("v_permlane32_swap_b32 %0, %1" : "+v"(pwA[4]), "+v"(pwA[6]));
        asm volatile("v_permlane32_swap_b32 %0, %1" : "+v"(pwA[5]), "+v"(pwA[7]));
        union { unsigned uu[4]; bf16x8 v; } pa0, pa1;
        pa0.uu[0] = pwA[0]; pa0.uu[1] = pwA[1]; pa0.uu[2] = pwA[2]; pa0.uu[3] = pwA[3];
        pa1.uu[0] = pwA[4]; pa1.uu[1] = pwA[5]; pa1.uu[2] = pwA[6]; pa1.uu[3] = pwA[7];

        __builtin_amdgcn_s_setprio(1);
        o0 = __builtin_amdgcn_mfma_f32_32x32x16_bf16(va0, pa0.v, o0, 0, 0, 0);
        o1 = __builtin_amdgcn_mfma_f32_32x32x16_bf16(vb0, pa0.v, o1, 0, 0, 0);
        o0 = __builtin_amdgcn_mfma_f32_32x32x16_bf16(va1, pa1.v, o0, 0, 0, 0);
        o1 = __builtin_amdgcn_mfma_f32_32x32x16_bf16(vb1, pa1.v, o1, 0, 0, 0);
        __builtin_amdgcn_s_setprio(0);
    }

    // per-wave partial -> LDS (O^T: lane col = q, regs = d)
    #pragma unroll
    for (int r = 0; r < 16; ++r) {
        const int d = (r & 3) + 8 * (r >> 2) + 4 * hi;
        Oall[w][col][d]      = o0[r];
        Oall[w][col][32 + d] = o1[r];
    }
    if (hi == 0) { Ml[w][col][0] = m_i; Ml[w][col][1] = l_i; }
    __syncthreads();

    if (tid < 32) {
        float M = Ml[0][tid][0];
        #pragma unroll
        for (int w2 = 1; w2 < 4; ++w2) M = fmaxf(M, Ml[w2][tid][0]);
        sM[tid] = M;
    }
    __syncthreads();
    if (tid < 128) {
        const int w2 = tid >> 5, r = tid & 31;
        sScl[w2][r] = EXP2(Ml[w2][r][0] - sM[r]);
    }
    __syncthreads();
    if (tid < 32) {
        float L = 0.f;
        #pragma unroll
        for (int w2 = 0; w2 < 4; ++w2) L += Ml[w2][tid][1] * sScl[w2][tid];
        sL[tid] = L;
    }
    __syncthreads();

    const int r = tid >> 3;
    const int c0 = (tid & 7) * 8;
    f32x4 a0 = (f32x4){0.f, 0.f, 0.f, 0.f};
    f32x4 a1 = (f32x4){0.f, 0.f, 0.f, 0.f};
    #pragma unroll
    for (int w2 = 0; w2 < 4; ++w2) {
        const float sc = sScl[w2][r];
        const float* Orow = &Oall[w2][r][c0];
        a0 += (*(const f32x4*)(Orow)) * sc;
        a1 += (*(const f32x4*)(Orow + 4)) * sc;
    }
    if (qt < 32) {   // single chunk: write final output
        const float inv = 1.f / sL[r];
        float* op = out + (size_t)(m0 + r) * DIM + c0;
        *(f32x4*)(op)     = a0 * inv;
        *(f32x4*)(op + 4) = a1 * inv;
    } else {         // write partial for fixup
        const int pb = 16 * (g - 1) * (g + 2) + (qt - 32 * g) * (g + 1) + cid;
        float* op = Opart + (size_t)pb * 2048 + r * 64 + c0;
        *(f32x4*)(op)     = a0;
        *(f32x4*)(op + 4) = a1;
        if (tid < 32) {
            MLpart[(size_t)pb * 64 + tid * 2]     = sM[tid];
            MLpart[(size_t)pb * 64 + tid * 2 + 1] = sL[tid];
        }
    }
}

// ---- Fixup: merge chunk partials for qt >= 32. 224 blocks x 256 ------------
__global__ __launch_bounds__(256) void fixup_kernel(
    const float* __restrict__ Opart, const float* __restrict__ MLpart,
    float* __restrict__ out)
{
    __shared__ float sScl[8][32];
    __shared__ float sInvL[32];

    const int qt = 32 + (int)blockIdx.x;
    const int g  = qt >> 5;
    const int nc = g + 1;
    const int pb = 16 * (g - 1) * (g + 2) + (qt - 32 * g) * nc;
    const int tid = (int)threadIdx.x;

    if (tid < 32) {
        float M = -1e30f;
        for (int c2 = 0; c2 < nc; ++c2)
            M = fmaxf(M, MLpart[(size_t)(pb + c2) * 64 + tid * 2]);
        float L = 0.f;
        for (int c2 = 0; c2 < nc; ++c2) {
            const float sc = EXP2(MLpart[(size_t)(pb + c2) * 64 + tid * 2] - M);
            sScl[c2][tid] = sc;
            L += MLpart[(size_t)(pb + c2) * 64 + tid * 2 + 1] * sc;
        }
        sInvL[tid] = 1.f / L;
    }
    __syncthreads();

    const int r = tid >> 3;
    const int c0 = (tid & 7) * 8;
    f32x4 a0 = (f32x4){0.f, 0.f, 0.f, 0.f};
    f32x4 a1 = (f32x4){0.f, 0.f, 0.f, 0.f};
    for (int c2 = 0; c2 < nc; ++c2) {
        const float sc = sScl[c2][r];
        const float* Op = Opart + (size_t)(pb + c2) * 2048 + r * 64 + c0;
        a0 += (*(const f32x4*)(Op)) * sc;
        a1 += (*(const f32x4*)(Op + 4)) * sc;
    }
    const float inv = sInvL[r];
    float* op = out + (size_t)(qt * 32 + r) * DIM + c0;
    *(f32x4*)(op)     = a0 * inv;
    *(f32x4*)(op + 4) = a1 * inv;
}

extern "C" void kernel_launch(void* const* d_in, const int* in_sizes, int n_in,
                              void* d_out, int out_size, void* d_ws, size_t ws_size,
                              hipStream_t stream) {
    const float* x  = (const float*)d_in[0];
    const float* y  = (const float*)d_in[1];
    const float* z  = (const float*)d_in[2];
    const float* Wq = (const float*)d_in[3];
    const float* bq = (const float*)d_in[4];
    const float* Wk = (const float*)d_in[5];
    const float* bk = (const float*)d_in[6];
    const float* Wv = (const float*)d_in[7];
    const float* bv = (const float*)d_in[8];

    unsigned short* qkv = (unsigned short*)d_ws;
    unsigned short* Wt  = (unsigned short*)((char*)d_ws + 3145728);
    float* Opart        = (float*)((char*)d_ws + 3538944);
    float* MLpart       = (float*)((char*)d_ws + 12713984);
    float* out          = (float*)d_out;

    hipLaunchKernelGGL(wt_kernel,    dim3(192),  dim3(256), 0, stream, Wq, Wk, Wv, Wt);
    hipLaunchKernelGGL(proj_kernel,  dim3(768),  dim3(128), 0, stream, x, y, z, bq, bk, bv, Wt, qkv);
    hipLaunchKernelGGL(attn_kernel,  dim3(1152), dim3(256), 0, stream, qkv, out, Opart, MLpart);
    hipLaunchKernelGGL(fixup_kernel, dim3(224),  dim3(256), 0, stream, Opart, MLpart, out);
}

// Round 4
// 90.994 us; speedup vs baseline: 1.6364x; 1.0011x over previous
//
#include <hip/hip_runtime.h>

#define SEQ 8192
#define EMB 1024
#define DIM 64

typedef __attribute__((ext_vector_type(8))) short bf16x8;
typedef __attribute__((ext_vector_type(4))) float f32x4;
typedef __attribute__((ext_vector_type(16))) float f32x16;

#if __has_builtin(__builtin_amdgcn_exp2f)
#define EXP2 __builtin_amdgcn_exp2f
#else
#define EXP2 exp2f
#endif

// softmax scale folded with log2(e): (1/sqrt(8192)) * 1.4426950408889634
#define SCL 0.0159396779f

__device__ inline unsigned short f2bf(float f) {
    union { float f; unsigned u; } x; x.f = f;
    unsigned r = x.u + 0x7FFFu + ((x.u >> 16) & 1u);
    return (unsigned short)(r >> 16);
}

__device__ inline unsigned cvtpk(float lo, float hi) {
    unsigned r;
    asm("v_cvt_pk_bf16_f32 %0, %1, %2" : "=v"(r) : "v"(lo), "v"(hi));
    return r;
}

// ---------------------------------------------------------------------------
// ws layout (bytes):
//  qkv    @ 0         : q[8192][64] | k[8192][64] | vT[64][8192]   bf16 (3,145,728)
//  Wt     @ 3145728   : [3][64][1024] bf16, k-PERMUTED layout (393,216)
//  Opart  @ 3538944   : [1120][32][64] f32 (9,175,040)
//  MLpart @ 12713984  : [1120][32][2]  f32 (286,720)
// ---------------------------------------------------------------------------

// ---- W transpose + bf16 + k-permute --------------------------------------
__global__ __launch_bounds__(256) void wt_kernel(
    const float* __restrict__ Wq, const float* __restrict__ Wk,
    const float* __restrict__ Wv, unsigned short* __restrict__ Wt)
{
    const int f = (int)blockIdx.x * 256 + (int)threadIdx.x;  // 49152 threads
    const int n    = f & 63;
    const int rest = f >> 6;
    const int mat  = rest >> 8;
    const int kp   = (rest & 255) * 4;      // k' base (multiple of 4)
    const float* W = (mat == 0) ? Wq : (mat == 1) ? Wk : Wv;
    const int w32 = kp & ~31;
    const int qq  = (kp >> 3) & 3;
    const int jg  = (kp >> 2) & 1;
    const int kb  = w32 + qq * 4 + jg * 16;
    unsigned short r0 = f2bf(W[(size_t)(kb + 0) * DIM + n]);
    unsigned short r1 = f2bf(W[(size_t)(kb + 1) * DIM + n]);
    unsigned short r2 = f2bf(W[(size_t)(kb + 2) * DIM + n]);
    unsigned short r3 = f2bf(W[(size_t)(kb + 3) * DIM + n]);
    unsigned* dst = (unsigned*)&Wt[(size_t)mat * 65536 + (size_t)n * 1024 + kp];
    dst[0] = (unsigned)r0 | ((unsigned)r1 << 16);
    dst[1] = (unsigned)r2 | ((unsigned)r3 << 16);
}

__device__ inline bf16x8 cvt8(float4 a, float4 b) {
    bf16x8 r;
    r[0] = (short)f2bf(a.x); r[1] = (short)f2bf(a.y);
    r[2] = (short)f2bf(a.z); r[3] = (short)f2bf(a.w);
    r[4] = (short)f2bf(b.x); r[5] = (short)f2bf(b.y);
    r[6] = (short)f2bf(b.z); r[7] = (short)f2bf(b.w);
    return r;
}

// ---- Projection: K-split-4, 1536 blocks x 256 thr (4 waves/block) ----------
// Block = 16 output rows; wave w reduces k-slice [w*256,(w+1)*256); LDS sum.
__global__ __launch_bounds__(256) void proj_kernel(
    const float* __restrict__ x, const float* __restrict__ y, const float* __restrict__ z,
    const float* __restrict__ bq, const float* __restrict__ bk, const float* __restrict__ bv,
    const unsigned short* __restrict__ Wt, unsigned short* __restrict__ qkv)
{
    __shared__ float Oall[4][16][68];

    const int bid = (int)blockIdx.x;
    const int mat = bid >> 9;                 // 0=q,1=k,2=v  (512 blocks each)
    const int rg  = bid & 511;
    const int rb  = rg * 16;

    const int tid  = (int)threadIdx.x;
    const int lane = tid & 63;
    const int w    = tid >> 6;                // k-slice id 0..3
    const int c    = lane & 15;
    const int qq   = lane >> 4;

    const float* X  = (mat == 0) ? x  : (mat == 1) ? y  : z;
    const float* Bv = (mat == 0) ? bq : (mat == 1) ? bk : bv;
    const unsigned short* Wm = Wt + (size_t)mat * (DIM * EMB);
    unsigned short* outp = qkv + (size_t)mat * (SEQ * DIM);

    f32x4 acc[4];
    #pragma unroll
    for (int nf = 0; nf < 4; ++nf) acc[nf] = (f32x4){0.f, 0.f, 0.f, 0.f};

    const float* Xr = X + (size_t)(rb + c) * EMB;
    const int cb = qq * 4;
    const int s0 = w * 8;                     // 8 k-steps of 32 per wave

    float4 A[4], B[4];
    #pragma unroll
    for (int i = 0; i < 4; ++i) {
        A[i] = *(const float4*)(Xr + (s0 + i) * 32 + cb);
        B[i] = *(const float4*)(Xr + (s0 + i) * 32 + 16 + cb);
    }

    #pragma unroll
    for (int so = 0; so < 2; ++so) {
        #pragma unroll
        for (int u2 = 0; u2 < 4; ++u2) {
            const int s = s0 + so * 4 + u2;
            bf16x8 af = cvt8(A[u2], B[u2]);
            if (so == 0) {
                A[u2] = *(const float4*)(Xr + (s + 4) * 32 + cb);
                B[u2] = *(const float4*)(Xr + (s + 4) * 32 + 16 + cb);
            }
            #pragma unroll
            for (int nf = 0; nf < 4; ++nf) {
                bf16x8 bfr = *(const bf16x8*)&Wm[(size_t)(nf * 16 + c) * EMB + s * 32 + qq * 8];
                acc[nf] = __builtin_amdgcn_mfma_f32_16x16x32_bf16(af, bfr, acc[nf], 0, 0, 0);
            }
        }
    }

    // write per-wave partial to LDS
    #pragma unroll
    for (int nf = 0; nf < 4; ++nf)
        #pragma unroll
        for (int i = 0; i < 4; ++i)
            Oall[w][qq * 4 + i][nf * 16 + c] = acc[nf][i];
    __syncthreads();

    // combine 4 k-slices + bias; 256 threads x 4 outputs
    const int e    = tid * 4;
    const int row  = e >> 6;        // 0..15
    const int col0 = e & 63;        // multiple of 4
    f32x4 sum = *(const f32x4*)&Oall[0][row][col0];
    #pragma unroll
    for (int w2 = 1; w2 < 4; ++w2) sum += *(const f32x4*)&Oall[w2][row][col0];
    sum += *(const f32x4*)&Bv[col0];

    if (mat != 2) {
        unsigned short* op = &outp[(size_t)(rb + row) * DIM + col0];
        unsigned* op2 = (unsigned*)op;
        op2[0] = cvtpk(sum[0], sum[1]);
        op2[1] = cvtpk(sum[2], sum[3]);
    } else {   // vT[d][row]
        #pragma unroll
        for (int i = 0; i < 4; ++i)
            outp[(size_t)(col0 + i) * SEQ + rb + row] = f2bf(sum[i]);
    }
}

// ---- Flash attention: swapped-operand 32x32, KVBLK=64 pairs, defer-max -----
// 1152 blocks x 256 thr (4 waves). Unit = (qtile, 32-tile KV chunk).
__global__ __launch_bounds__(256, 3) void attn_kernel(
    const unsigned short* __restrict__ qkv, float* __restrict__ out,
    float* __restrict__ Opart, float* __restrict__ MLpart)
{
    const unsigned short* Q  = qkv;
    const unsigned short* K  = qkv + SEQ * DIM;
    const unsigned short* Vt = qkv + 2 * SEQ * DIM;   // [64][8192]

    __shared__ float Oall[4][32][68];
    __shared__ float Ml[4][32][2];
    __shared__ float sScl[4][32];
    __shared__ float sM[32];
    __shared__ float sL[32];

    // unit id, longest-first
    const int u = 1151 - (int)blockIdx.x;
    int g;
    if (u < 32) g = 0; else if (u < 96) g = 1; else if (u < 192) g = 2;
    else if (u < 320) g = 3; else if (u < 480) g = 4; else if (u < 672) g = 5;
    else if (u < 896) g = 6; else g = 7;
    const int o_  = u - 16 * g * (g + 1);
    const int qt  = 32 * g + o_ / (g + 1);
    const int cid = o_ - (o_ / (g + 1)) * (g + 1);

    const int m0 = qt * 32;
    const int tid = (int)threadIdx.x;
    const int lane = tid & 63;
    const int w = tid >> 6;        // 0..3
    const int col = lane & 31;     // q row within tile
    const int hi = lane >> 5;

    // Q fragments (B-operand)
    bf16x8 qf[4];
    {
        const unsigned short* Qr = Q + (size_t)(m0 + col) * DIM + hi * 8;
        #pragma unroll
        for (int ks = 0; ks < 4; ++ks) qf[ks] = *(const bf16x8*)(Qr + ks * 16);
    }

    f32x16 o0, o1;
    #pragma unroll
    for (int r = 0; r < 16; ++r) { o0[r] = 0.f; o1[r] = 0.f; }
    float m_i = -1e30f, l_i = 0.f;

    const int nT = qt + 1;
    const int tb = cid * 32;
    const int te = (tb + 32 < nT) ? (tb + 32) : nT;
    const int nC = te - tb;
    const int w0 = tb + ((nC * w) >> 2);
    const int w1 = tb + ((nC * (w + 1)) >> 2);
    const int nW = w1 - w0;
    const int nP = nW >> 1;

    for (int pi = 0; pi < nP; ++pi) {
        const int t = w0 + 2 * pi;
        const int n0 = t * 32;
        // ---- load K (both tiles) and V (both tiles) up-front ----
        const unsigned short* KrA = K + (size_t)(n0 + col) * DIM + hi * 8;
        bf16x8 kA[4], kB[4];
        #pragma unroll
        for (int ks = 0; ks < 4; ++ks) kA[ks] = *(const bf16x8*)(KrA + ks * 16);
        #pragma unroll
        for (int ks = 0; ks < 4; ++ks) kB[ks] = *(const bf16x8*)(KrA + 32 * DIM + ks * 16);
        const unsigned short* Vr0 = Vt + (size_t)col * SEQ + n0 + hi * 8;
        const unsigned short* Vr1 = Vr0 + 32 * SEQ;
        bf16x8 va[4], vb[4];
        #pragma unroll
        for (int i = 0; i < 4; ++i) va[i] = *(const bf16x8*)(Vr0 + i * 16);
        #pragma unroll
        for (int i = 0; i < 4; ++i) vb[i] = *(const bf16x8*)(Vr1 + i * 16);

        // ---- dual QK chains ----
        f32x16 sa, sb;
        #pragma unroll
        for (int r = 0; r < 16; ++r) { sa[r] = 0.f; sb[r] = 0.f; }
        __builtin_amdgcn_s_setprio(1);
        #pragma unroll
        for (int ks = 0; ks < 4; ++ks) {
            sa = __builtin_amdgcn_mfma_f32_32x32x16_bf16(kA[ks], qf[ks], sa, 0, 0, 0);
            sb = __builtin_amdgcn_mfma_f32_32x32x16_bf16(kB[ks], qf[ks], sb, 0, 0, 0);
        }
        __builtin_amdgcn_s_setprio(0);

        float p0[16], p1[16];
        #pragma unroll
        for (int r = 0; r < 16; ++r) { p0[r] = sa[r] * SCL; p1[r] = sb[r] * SCL; }
        if (t + 1 == qt) {   // diagonal can only be the second tile of a pair
            #pragma unroll
            for (int r = 0; r < 16; ++r) {
                const int kvr = (r & 3) + 8 * (r >> 2) + 4 * hi;
                if (kvr > col) p1[r] = -1e30f;
            }
        }
        // ---- row max over 64 kv ----
        float tm = fmaxf(p0[0], p1[0]);
        #pragma unroll
        for (int r = 1; r < 16; ++r) tm = fmaxf(tm, fmaxf(p0[r], p1[r]));
        tm = fmaxf(tm, __shfl_xor(tm, 32));
        // ---- defer-max: skip rescale when max didn't grow past margin ----
        if (!__all(tm <= m_i + 2.0f)) {
            const float mn = fmaxf(m_i, tm);
            const float alpha = EXP2(m_i - mn);
            m_i = mn;
            l_i *= alpha;
            #pragma unroll
            for (int r = 0; r < 16; ++r) { o0[r] *= alpha; o1[r] *= alpha; }
        }
        float rs = 0.f;
        #pragma unroll
        for (int r = 0; r < 16; ++r) { p0[r] = EXP2(p0[r] - m_i); rs += p0[r]; }
        #pragma unroll
        for (int r = 0; r < 16; ++r) { p1[r] = EXP2(p1[r] - m_i); rs += p1[r]; }
        rs += __shfl_xor(rs, 32);
        l_i += rs;

        // ---- pack P -> bf16 (cvt_pk) + permlane32_swap -> B-fragments ----
        unsigned pwA[8], pwB[8];
        #pragma unroll
        for (int i = 0; i < 8; ++i) pwA[i] = cvtpk(p0[2 * i], p0[2 * i + 1]);
        #pragma unroll
        for (int i = 0; i < 8; ++i) pwB[i] = cvtpk(p1[2 * i], p1[2 * i + 1]);
        asm volatile("v_permlane32_swap_b32 %0, %1" : "+v"(pwA[0]), "+v"(pwA[2]));
        asm volatile("v_permlane32_swap_b32 %0, %1" : "+v"(pwA[1]), "+v"(pwA[3]));
        asm volatile("v_permlane32_swap_b32 %0, %1" : "+v"(pwA[4]), "+v"(pwA[6]));
        asm volatile("v_permlane32_swap_b32 %0, %1" : "+v"(pwA[5]), "+v"(pwA[7]));
        asm volatile("v_permlane32_swap_b32 %0, %1" : "+v"(pwB[0]), "+v"(pwB[2]));
        asm volatile("v_permlane32_swap_b32 %0, %1" : "+v"(pwB[1]), "+v"(pwB[3]));
        asm volatile("v_permlane32_swap_b32 %0, %1" : "+v"(pwB[4]), "+v"(pwB[6]));
        asm volatile("v_permlane32_swap_b32 %0, %1" : "+v"(pwB[5]), "+v"(pwB[7]));
        union { unsigned uu[4]; bf16x8 v; } pa0, pa1, pb0, pb1;
        pa0.uu[0] = pwA[0]; pa0.uu[1] = pwA[1]; pa0.uu[2] = pwA[2]; pa0.uu[3] = pwA[3];
        pa1.uu[0] = pwA[4]; pa1.uu[1] = pwA[5]; pa1.uu[2] = pwA[6]; pa1.uu[3] = pwA[7];
        pb0.uu[0] = pwB[0]; pb0.uu[1] = pwB[1]; pb0.uu[2] = pwB[2]; pb0.uu[3] = pwB[3];
        pb1.uu[0] = pwB[4]; pb1.uu[1] = pwB[5]; pb1.uu[2] = pwB[6]; pb1.uu[3] = pwB[7];

        // ---- O^T += V^T . P^T ----
        __builtin_amdgcn_s_setprio(1);
        o0 = __builtin_amdgcn_mfma_f32_32x32x16_bf16(va[0], pa0.v, o0, 0, 0, 0);
        o1 = __builtin_amdgcn_mfma_f32_32x32x16_bf16(vb[0], pa0.v, o1, 0, 0, 0);
        o0 = __builtin_amdgcn_mfma_f32_32x32x16_bf16(va[1], pa1.v, o0, 0, 0, 0);
        o1 = __builtin_amdgcn_mfma_f32_32x32x16_bf16(vb[1], pa1.v, o1, 0, 0, 0);
        o0 = __builtin_amdgcn_mfma_f32_32x32x16_bf16(va[2], pb0.v, o0, 0, 0, 0);
        o1 = __builtin_amdgcn_mfma_f32_32x32x16_bf16(vb[2], pb0.v, o1, 0, 0, 0);
        o0 = __builtin_amdgcn_mfma_f32_32x32x16_bf16(va[3], pb1.v, o0, 0, 0, 0);
        o1 = __builtin_amdgcn_mfma_f32_32x32x16_bf16(vb[3], pb1.v, o1, 0, 0, 0);
        __builtin_amdgcn_s_setprio(0);
    }

    if (nW & 1) {   // tail single tile
        const int t = w1 - 1;
        const int n0 = t * 32;
        const unsigned short* Kr = K + (size_t)(n0 + col) * DIM + hi * 8;
        bf16x8 kA[4];
        #pragma unroll
        for (int ks = 0; ks < 4; ++ks) kA[ks] = *(const bf16x8*)(Kr + ks * 16);
        const unsigned short* Vr0 = Vt + (size_t)col * SEQ + n0 + hi * 8;
        const unsigned short* Vr1 = Vr0 + 32 * SEQ;
        bf16x8 va0 = *(const bf16x8*)(Vr0);
        bf16x8 va1 = *(const bf16x8*)(Vr0 + 16);
        bf16x8 vb0 = *(const bf16x8*)(Vr1);
        bf16x8 vb1 = *(const bf16x8*)(Vr1 + 16);

        f32x16 sa;
        #pragma unroll
        for (int r = 0; r < 16; ++r) sa[r] = 0.f;
        __builtin_amdgcn_s_setprio(1);
        #pragma unroll
        for (int ks = 0; ks < 4; ++ks)
            sa = __builtin_amdgcn_mfma_f32_32x32x16_bf16(kA[ks], qf[ks], sa, 0, 0, 0);
        __builtin_amdgcn_s_setprio(0);

        float p0[16];
        #pragma unroll
        for (int r = 0; r < 16; ++r) p0[r] = sa[r] * SCL;
        if (t == qt) {
            #pragma unroll
            for (int r = 0; r < 16; ++r) {
                const int kvr = (r & 3) + 8 * (r >> 2) + 4 * hi;
                if (kvr > col) p0[r] = -1e30f;
            }
        }
        float tm = p0[0];
        #pragma unroll
        for (int r = 1; r < 16; ++r) tm = fmaxf(tm, p0[r]);
        tm = fmaxf(tm, __shfl_xor(tm, 32));
        if (!__all(tm <= m_i + 2.0f)) {
            const float mn = fmaxf(m_i, tm);
            const float alpha = EXP2(m_i - mn);
            m_i = mn;
            l_i *= alpha;
            #pragma unroll
            for (int r = 0; r < 16; ++r) { o0[r] *= alpha; o1[r] *= alpha; }
        }
        float rs = 0.f;
        #pragma unroll
        for (int r = 0; r < 16; ++r) { p0[r] = EXP2(p0[r] - m_i); rs += p0[r]; }
        rs += __shfl_xor(rs, 32);
        l_i += rs;

        unsigned pwA[8];
        #pragma unroll
        for (int i = 0; i < 8; ++i) pwA[i] = cvtpk(p0[2 * i], p0[2 * i + 1]);
        asm volatile("v_permlane32_swap_b32 %0, %1" : "+v"(pwA[0]), "+v"(pwA[2]));
        asm volatile("v_permlane32_swap_b32 %0, %1" : "+v"(pwA[1]), "+v"(pwA[3]));
        asm volatile("v_permlane32_swap_b32 %0, %1" : "+v"(pwA[4]), "+v"(pwA[6]));
        asm volatile("v_permlane32_swap_b32 %0, %1" : "+v"(pwA[5]), "+v"(pwA[7]));
        union { unsigned uu[4]; bf16x8 v; } pa0, pa1;
        pa0.uu[0] = pwA[0]; pa0.uu[1] = pwA[1]; pa0.uu[2] = pwA[2]; pa0.uu[3] = pwA[3];
        pa1.uu[0] = pwA[4]; pa1.uu[1] = pwA[5]; pa1.uu[2] = pwA[6]; pa1.uu[3] = pwA[7];

        __builtin_amdgcn_s_setprio(1);
        o0 = __builtin_amdgcn_mfma_f32_32x32x16_bf16(va0, pa0.v, o0, 0, 0, 0);
        o1 = __builtin_amdgcn_mfma_f32_32x32x16_bf16(vb0, pa0.v, o1, 0, 0, 0);
        o0 = __builtin_amdgcn_mfma_f32_32x32x16_bf16(va1, pa1.v, o0, 0, 0, 0);
        o1 = __builtin_amdgcn_mfma_f32_32x32x16_bf16(vb1, pa1.v, o1, 0, 0, 0);
        __builtin_amdgcn_s_setprio(0);
    }

    // per-wave partial -> LDS (O^T: lane col = q, regs = d)
    #pragma unroll
    for (int r = 0; r < 16; ++r) {
        const int d = (r & 3) + 8 * (r >> 2) + 4 * hi;
        Oall[w][col][d]      = o0[r];
        Oall[w][col][32 + d] = o1[r];
    }
    if (hi == 0) { Ml[w][col][0] = m_i; Ml[w][col][1] = l_i; }
    __syncthreads();

    if (tid < 32) {
        float M = Ml[0][tid][0];
        #pragma unroll
        for (int w2 = 1; w2 < 4; ++w2) M = fmaxf(M, Ml[w2][tid][0]);
        sM[tid] = M;
    }
    __syncthreads();
    if (tid < 128) {
        const int w2 = tid >> 5, r = tid & 31;
        sScl[w2][r] = EXP2(Ml[w2][r][0] - sM[r]);
    }
    __syncthreads();
    if (tid < 32) {
        float L = 0.f;
        #pragma unroll
        for (int w2 = 0; w2 < 4; ++w2) L += Ml[w2][tid][1] * sScl[w2][tid];
        sL[tid] = L;
    }
    __syncthreads();

    const int r = tid >> 3;
    const int c0 = (tid & 7) * 8;
    f32x4 a0 = (f32x4){0.f, 0.f, 0.f, 0.f};
    f32x4 a1 = (f32x4){0.f, 0.f, 0.f, 0.f};
    #pragma unroll
    for (int w2 = 0; w2 < 4; ++w2) {
        const float sc = sScl[w2][r];
        const float* Orow = &Oall[w2][r][c0];
        a0 += (*(const f32x4*)(Orow)) * sc;
        a1 += (*(const f32x4*)(Orow + 4)) * sc;
    }
    if (qt < 32) {   // single chunk: write final output
        const float inv = 1.f / sL[r];
        float* op = out + (size_t)(m0 + r) * DIM + c0;
        *(f32x4*)(op)     = a0 * inv;
        *(f32x4*)(op + 4) = a1 * inv;
    } else {         // write partial for fixup
        const int pb = 16 * (g - 1) * (g + 2) + (qt - 32 * g) * (g + 1) + cid;
        float* op = Opart + (size_t)pb * 2048 + r * 64 + c0;
        *(f32x4*)(op)     = a0;
        *(f32x4*)(op + 4) = a1;
        if (tid < 32) {
            MLpart[(size_t)pb * 64 + tid * 2]     = sM[tid];
            MLpart[(size_t)pb * 64 + tid * 2 + 1] = sL[tid];
        }
    }
}

// ---- Fixup: merge chunk partials for qt >= 32. 224 blocks x 256 ------------
__global__ __launch_bounds__(256) void fixup_kernel(
    const float* __restrict__ Opart, const float* __restrict__ MLpart,
    float* __restrict__ out)
{
    __shared__ float sScl[8][32];
    __shared__ float sInvL[32];

    const int qt = 32 + (int)blockIdx.x;
    const int g  = qt >> 5;
    const int nc = g + 1;
    const int pb = 16 * (g - 1) * (g + 2) + (qt - 32 * g) * nc;
    const int tid = (int)threadIdx.x;

    if (tid < 32) {
        float M = -1e30f;
        for (int c2 = 0; c2 < nc; ++c2)
            M = fmaxf(M, MLpart[(size_t)(pb + c2) * 64 + tid * 2]);
        float L = 0.f;
        for (int c2 = 0; c2 < nc; ++c2) {
            const float sc = EXP2(MLpart[(size_t)(pb + c2) * 64 + tid * 2] - M);
            sScl[c2][tid] = sc;
            L += MLpart[(size_t)(pb + c2) * 64 + tid * 2 + 1] * sc;
        }
        sInvL[tid] = 1.f / L;
    }
    __syncthreads();

    const int r = tid >> 3;
    const int c0 = (tid & 7) * 8;
    f32x4 a0 = (f32x4){0.f, 0.f, 0.f, 0.f};
    f32x4 a1 = (f32x4){0.f, 0.f, 0.f, 0.f};
    for (int c2 = 0; c2 < nc; ++c2) {
        const float sc = sScl[c2][r];
        const float* Op = Opart + (size_t)(pb + c2) * 2048 + r * 64 + c0;
        a0 += (*(const f32x4*)(Op)) * sc;
        a1 += (*(const f32x4*)(Op + 4)) * sc;
    }
    const float inv = sInvL[r];
    float* op = out + (size_t)(qt * 32 + r) * DIM + c0;
    *(f32x4*)(op)     = a0 * inv;
    *(f32x4*)(op + 4) = a1 * inv;
}

extern "C" void kernel_launch(void* const* d_in, const int* in_sizes, int n_in,
                              void* d_out, int out_size, void* d_ws, size_t ws_size,
                              hipStream_t stream) {
    const float* x  = (const float*)d_in[0];
    const float* y  = (const float*)d_in[1];
    const float* z  = (const float*)d_in[2];
    const float* Wq = (const float*)d_in[3];
    const float* bq = (const float*)d_in[4];
    const float* Wk = (const float*)d_in[5];
    const float* bk = (const float*)d_in[6];
    const float* Wv = (const float*)d_in[7];
    const float* bv = (const float*)d_in[8];

    unsigned short* qkv = (unsigned short*)d_ws;
    unsigned short* Wt  = (unsigned short*)((char*)d_ws + 3145728);
    float* Opart        = (float*)((char*)d_ws + 3538944);
    float* MLpart       = (float*)((char*)d_ws + 12713984);
    float* out          = (float*)d_out;

    hipLaunchKernelGGL(wt_kernel,    dim3(192),  dim3(256), 0, stream, Wq, Wk, Wv, Wt);
    hipLaunchKernelGGL(proj_kernel,  dim3(1536), dim3(256), 0, stream, x, y, z, bq, bk, bv, Wt, qkv);
    hipLaunchKernelGGL(attn_kernel,  dim3(1152), dim3(256), 0, stream, qkv, out, Opart, MLpart);
    hipLaunchKernelGGL(fixup_kernel, dim3(224),  dim3(256), 0, stream, Opart, MLpart, out);
}

// Round 5
// 87.324 us; speedup vs baseline: 1.7052x; 1.0420x over previous
//
#include <hip/hip_runtime.h>

#define SEQ 8192
#define EMB 1024
#define DIM 64

typedef __attribute__((ext_vector_type(8))) short bf16x8;
typedef __attribute__((ext_vector_type(4))) float f32x4;
typedef __attribute__((ext_vector_type(16))) float f32x16;

#if __has_builtin(__builtin_amdgcn_exp2f)
#define EXP2 __builtin_amdgcn_exp2f
#else
#define EXP2 exp2f
#endif

// softmax scale folded with log2(e): (1/sqrt(8192)) * 1.4426950408889634
#define SCL 0.0159396779f

__device__ inline unsigned short f2bf(float f) {
    union { float f; unsigned u; } x; x.f = f;
    unsigned r = x.u + 0x7FFFu + ((x.u >> 16) & 1u);
    return (unsigned short)(r >> 16);
}

__device__ inline unsigned cvtpk(float lo, float hi) {
    unsigned r;
    asm("v_cvt_pk_bf16_f32 %0, %1, %2" : "=v"(r) : "v"(lo), "v"(hi));
    return r;
}

__device__ __forceinline__ void gload16(const float* g, float* l) {
    __builtin_amdgcn_global_load_lds(
        (const __attribute__((address_space(1))) unsigned*)g,
        (__attribute__((address_space(3))) unsigned*)l, 16, 0, 0);
}

// ---------------------------------------------------------------------------
// ws layout (bytes):
//  qkv    @ 0         : q[8192][64] | k[8192][64] | vT[64][8192]   bf16 (3,145,728)
//  Wt     @ 3145728   : [3][64][1024] bf16 plain transpose (393,216)
//  Opart  @ 3538944   : [1120][32][64] f32 (9,175,040)
//  MLpart @ 12713984  : [1120][32][2]  f32 (286,720)
// ---------------------------------------------------------------------------

// ---- W transpose + bf16: Wt[mat][n][k] = bf16(W[k][n]) ---------------------
__global__ __launch_bounds__(256) void wt_kernel(
    const float* __restrict__ Wq, const float* __restrict__ Wk,
    const float* __restrict__ Wv, unsigned short* __restrict__ Wt)
{
    const int f = (int)blockIdx.x * 256 + (int)threadIdx.x;  // 49152 threads
    const int n    = f & 63;
    const int rest = f >> 6;
    const int mat  = rest >> 8;
    const int kp   = (rest & 255) * 4;      // k base (multiple of 4)
    const float* W = (mat == 0) ? Wq : (mat == 1) ? Wk : Wv;
    unsigned short r0 = f2bf(W[(size_t)(kp + 0) * DIM + n]);
    unsigned short r1 = f2bf(W[(size_t)(kp + 1) * DIM + n]);
    unsigned short r2 = f2bf(W[(size_t)(kp + 2) * DIM + n]);
    unsigned short r3 = f2bf(W[(size_t)(kp + 3) * DIM + n]);
    unsigned* dst = (unsigned*)&Wt[(size_t)mat * 65536 + (size_t)n * 1024 + kp];
    dst[0] = (unsigned)r0 | ((unsigned)r1 << 16);
    dst[1] = (unsigned)r2 | ((unsigned)r3 << 16);
}

__device__ inline bf16x8 cvt8(float4 a, float4 b) {
    bf16x8 r;
    r[0] = (short)f2bf(a.x); r[1] = (short)f2bf(a.y);
    r[2] = (short)f2bf(a.z); r[3] = (short)f2bf(a.w);
    r[4] = (short)f2bf(b.x); r[5] = (short)f2bf(b.y);
    r[6] = (short)f2bf(b.z); r[7] = (short)f2bf(b.w);
    return r;
}

// ---- Projection: global_load_lds staged, stream-coalesced ------------------
// 768 blocks x 512 thr (8 waves). Block = 32 rows x 64 cols; K tiled at 256.
// LDS [2][32][256] f32 (64 KB), XOR-swizzled via pre-swizzled global source.
__global__ __launch_bounds__(512) void proj_kernel(
    const float* __restrict__ x, const float* __restrict__ y, const float* __restrict__ z,
    const float* __restrict__ bq, const float* __restrict__ bk, const float* __restrict__ bv,
    const unsigned short* __restrict__ Wt, unsigned short* __restrict__ qkv)
{
    __shared__ float tile[2][32][256];

    const int bid = (int)blockIdx.x;
    const int mat = bid >> 8;                 // 0=q,1=k,2=v (256 blocks each)
    const int rb  = (bid & 255) * 32;

    const int tid  = (int)threadIdx.x;
    const int lane = tid & 63;
    const int w    = tid >> 6;                // 0..7
    const int wr   = w >> 2;                  // row-tile 0..1
    const int wc   = w & 3;                   // col-tile 0..3
    const int c    = lane & 15;
    const int qq   = lane >> 4;

    const float* X  = (mat == 0) ? x  : (mat == 1) ? y  : z;
    const float* Bv = (mat == 0) ? bq : (mat == 1) ? bk : bv;
    const unsigned short* Wm = Wt + (size_t)mat * (DIM * EMB);
    unsigned short* outp = qkv + (size_t)mat * (SEQ * DIM);

    f32x4 acc = (f32x4){0.f, 0.f, 0.f, 0.f};

    const int arow = wr * 16 + c;             // A-fragment LDS row
    const int sw   = (c & 7) << 4;            // read-side XOR (bytes)
    const char* rb0 = (const char*)&tile[0][arow][0];
    const char* rb1 = (const char*)&tile[1][arow][0];
    const unsigned short* Wrow = &Wm[(size_t)(wc * 16 + c) * EMB + qq * 8];

    // stage K-tile t into buffer nb: wave w loads rows w*4..w*4+3
    #define STAGE(nb, t)                                                        \
        {                                                                       \
            const int k0_ = (t) * 256;                                          \
            _Pragma("unroll")                                                   \
            for (int j = 0; j < 4; ++j) {                                       \
                const int r_ = w * 4 + j;                                       \
                const float* src_ = X + (size_t)(rb + r_) * EMB + k0_           \
                                      + ((lane ^ (r_ & 7)) << 2);               \
                gload16(src_, &tile[nb][r_][0]);                                \
            }                                                                   \
        }

    STAGE(0, 0);
    __syncthreads();

    int buf = 0;
    #pragma unroll
    for (int t = 0; t < 4; ++t) {
        if (t < 3) STAGE(buf ^ 1, t + 1);
        const char* rowb = buf ? rb1 : rb0;
        #pragma unroll
        for (int s = 0; s < 8; ++s) {
            const int base = s * 128 + qq * 32;
            float4 fa = *(const float4*)(rowb + ((base) ^ sw));
            float4 fb = *(const float4*)(rowb + ((base + 16) ^ sw));
            bf16x8 af = cvt8(fa, fb);
            bf16x8 bfr = *(const bf16x8*)(Wrow + t * 256 + s * 32);
            acc = __builtin_amdgcn_mfma_f32_16x16x32_bf16(af, bfr, acc, 0, 0, 0);
        }
        __syncthreads();
        buf ^= 1;
    }
    #undef STAGE

    // epilogue: + bias, bf16, store (v transposed)
    const int col = wc * 16 + c;
    const float bb = Bv[col];
    if (mat != 2) {
        #pragma unroll
        for (int i = 0; i < 4; ++i) {
            const int row = rb + wr * 16 + qq * 4 + i;
            outp[(size_t)row * DIM + col] = f2bf(acc[i] + bb);
        }
    } else {   // vT[d][row], 4 consecutive rows -> one 8B store
        unsigned short v0 = f2bf(acc[0] + bb), v1 = f2bf(acc[1] + bb);
        unsigned short v2 = f2bf(acc[2] + bb), v3 = f2bf(acc[3] + bb);
        uint2 pk;
        pk.x = (unsigned)v0 | ((unsigned)v1 << 16);
        pk.y = (unsigned)v2 | ((unsigned)v3 << 16);
        *(uint2*)&outp[(size_t)col * SEQ + rb + wr * 16 + qq * 4] = pk;
    }
}

// ---- Flash attention: swapped-operand 32x32, KVBLK=64 pairs, defer-max -----
// 1152 blocks x 256 thr (4 waves). Unit = (qtile, 32-tile KV chunk).
__global__ __launch_bounds__(256, 3) void attn_kernel(
    const unsigned short* __restrict__ qkv, float* __restrict__ out,
    float* __restrict__ Opart, float* __restrict__ MLpart)
{
    const unsigned short* Q  = qkv;
    const unsigned short* K  = qkv + SEQ * DIM;
    const unsigned short* Vt = qkv + 2 * SEQ * DIM;   // [64][8192]

    __shared__ float Oall[4][32][68];
    __shared__ float Ml[4][32][2];
    __shared__ float sScl[4][32];
    __shared__ float sM[32];
    __shared__ float sL[32];

    // unit id, longest-first
    const int u = 1151 - (int)blockIdx.x;
    int g;
    if (u < 32) g = 0; else if (u < 96) g = 1; else if (u < 192) g = 2;
    else if (u < 320) g = 3; else if (u < 480) g = 4; else if (u < 672) g = 5;
    else if (u < 896) g = 6; else g = 7;
    const int o_  = u - 16 * g * (g + 1);
    const int qt  = 32 * g + o_ / (g + 1);
    const int cid = o_ - (o_ / (g + 1)) * (g + 1);

    const int m0 = qt * 32;
    const int tid = (int)threadIdx.x;
    const int lane = tid & 63;
    const int w = tid >> 6;        // 0..3
    const int col = lane & 31;     // q row within tile
    const int hi = lane >> 5;

    // Q fragments (B-operand)
    bf16x8 qf[4];
    {
        const unsigned short* Qr = Q + (size_t)(m0 + col) * DIM + hi * 8;
        #pragma unroll
        for (int ks = 0; ks < 4; ++ks) qf[ks] = *(const bf16x8*)(Qr + ks * 16);
    }

    f32x16 o0, o1;
    #pragma unroll
    for (int r = 0; r < 16; ++r) { o0[r] = 0.f; o1[r] = 0.f; }
    float m_i = -1e30f, l_i = 0.f;

    const int nT = qt + 1;
    const int tb = cid * 32;
    const int te = (tb + 32 < nT) ? (tb + 32) : nT;
    const int nC = te - tb;
    const int w0 = tb + ((nC * w) >> 2);
    const int w1 = tb + ((nC * (w + 1)) >> 2);
    const int nW = w1 - w0;
    const int nP = nW >> 1;

    for (int pi = 0; pi < nP; ++pi) {
        const int t = w0 + 2 * pi;
        const int n0 = t * 32;
        // ---- load K (both tiles) and V (both tiles) up-front ----
        const unsigned short* KrA = K + (size_t)(n0 + col) * DIM + hi * 8;
        bf16x8 kA[4], kB[4];
        #pragma unroll
        for (int ks = 0; ks < 4; ++ks) kA[ks] = *(const bf16x8*)(KrA + ks * 16);
        #pragma unroll
        for (int ks = 0; ks < 4; ++ks) kB[ks] = *(const bf16x8*)(KrA + 32 * DIM + ks * 16);
        const unsigned short* Vr0 = Vt + (size_t)col * SEQ + n0 + hi * 8;
        const unsigned short* Vr1 = Vr0 + 32 * SEQ;
        bf16x8 va[4], vb[4];
        #pragma unroll
        for (int i = 0; i < 4; ++i) va[i] = *(const bf16x8*)(Vr0 + i * 16);
        #pragma unroll
        for (int i = 0; i < 4; ++i) vb[i] = *(const bf16x8*)(Vr1 + i * 16);

        // ---- dual QK chains ----
        f32x16 sa, sb;
        #pragma unroll
        for (int r = 0; r < 16; ++r) { sa[r] = 0.f; sb[r] = 0.f; }
        __builtin_amdgcn_s_setprio(1);
        #pragma unroll
        for (int ks = 0; ks < 4; ++ks) {
            sa = __builtin_amdgcn_mfma_f32_32x32x16_bf16(kA[ks], qf[ks], sa, 0, 0, 0);
            sb = __builtin_amdgcn_mfma_f32_32x32x16_bf16(kB[ks], qf[ks], sb, 0, 0, 0);
        }
        __builtin_amdgcn_s_setprio(0);

        float p0[16], p1[16];
        #pragma unroll
        for (int r = 0; r < 16; ++r) { p0[r] = sa[r] * SCL; p1[r] = sb[r] * SCL; }
        if (t + 1 == qt) {   // diagonal can only be the second tile of a pair
            #pragma unroll
            for (int r = 0; r < 16; ++r) {
                const int kvr = (r & 3) + 8 * (r >> 2) + 4 * hi;
                if (kvr > col) p1[r] = -1e30f;
            }
        }
        // ---- row max over 64 kv ----
        float tm = fmaxf(p0[0], p1[0]);
        #pragma unroll
        for (int r = 1; r < 16; ++r) tm = fmaxf(tm, fmaxf(p0[r], p1[r]));
        tm = fmaxf(tm, __shfl_xor(tm, 32));
        // ---- defer-max: skip rescale when max didn't grow past margin ----
        if (!__all(tm <= m_i + 2.0f)) {
            const float mn = fmaxf(m_i, tm);
            const float alpha = EXP2(m_i - mn);
            m_i = mn;
            l_i *= alpha;
            #pragma unroll
            for (int r = 0; r < 16; ++r) { o0[r] *= alpha; o1[r] *= alpha; }
        }
        float rs = 0.f;
        #pragma unroll
        for (int r = 0; r < 16; ++r) { p0[r] = EXP2(p0[r] - m_i); rs += p0[r]; }
        #pragma unroll
        for (int r = 0; r < 16; ++r) { p1[r] = EXP2(p1[r] - m_i); rs += p1[r]; }
        rs += __shfl_xor(rs, 32);
        l_i += rs;

        // ---- pack P -> bf16 (cvt_pk) + permlane32_swap -> B-fragments ----
        unsigned pwA[8], pwB[8];
        #pragma unroll
        for (int i = 0; i < 8; ++i) pwA[i] = cvtpk(p0[2 * i], p0[2 * i + 1]);
        #pragma unroll
        for (int i = 0; i < 8; ++i) pwB[i] = cvtpk(p1[2 * i], p1[2 * i + 1]);
        asm volatile("v_permlane32_swap_b32 %0, %1" : "+v"(pwA[0]), "+v"(pwA[2]));
        asm volatile("v_permlane32_swap_b32 %0, %1" : "+v"(pwA[1]), "+v"(pwA[3]));
        asm volatile("v_permlane32_swap_b32 %0, %1" : "+v"(pwA[4]), "+v"(pwA[6]));
        asm volatile("v_permlane32_swap_b32 %0, %1" : "+v"(pwA[5]), "+v"(pwA[7]));
        asm volatile("v_permlane32_swap_b32 %0, %1" : "+v"(pwB[0]), "+v"(pwB[2]));
        asm volatile("v_permlane32_swap_b32 %0, %1" : "+v"(pwB[1]), "+v"(pwB[3]));
        asm volatile("v_permlane32_swap_b32 %0, %1" : "+v"(pwB[4]), "+v"(pwB[6]));
        asm volatile("v_permlane32_swap_b32 %0, %1" : "+v"(pwB[5]), "+v"(pwB[7]));
        union { unsigned uu[4]; bf16x8 v; } pa0, pa1, pb0, pb1;
        pa0.uu[0] = pwA[0]; pa0.uu[1] = pwA[1]; pa0.uu[2] = pwA[2]; pa0.uu[3] = pwA[3];
        pa1.uu[0] = pwA[4]; pa1.uu[1] = pwA[5]; pa1.uu[2] = pwA[6]; pa1.uu[3] = pwA[7];
        pb0.uu[0] = pwB[0]; pb0.uu[1] = pwB[1]; pb0.uu[2] = pwB[2]; pb0.uu[3] = pwB[3];
        pb1.uu[0] = pwB[4]; pb1.uu[1] = pwB[5]; pb1.uu[2] = pwB[6]; pb1.uu[3] = pwB[7];

        // ---- O^T += V^T . P^T ----
        __builtin_amdgcn_s_setprio(1);
        o0 = __builtin_amdgcn_mfma_f32_32x32x16_bf16(va[0], pa0.v, o0, 0, 0, 0);
        o1 = __builtin_amdgcn_mfma_f32_32x32x16_bf16(vb[0], pa0.v, o1, 0, 0, 0);
        o0 = __builtin_amdgcn_mfma_f32_32x32x16_bf16(va[1], pa1.v, o0, 0, 0, 0);
        o1 = __builtin_amdgcn_mfma_f32_32x32x16_bf16(vb[1], pa1.v, o1, 0, 0, 0);
        o0 = __builtin_amdgcn_mfma_f32_32x32x16_bf16(va[2], pb0.v, o0, 0, 0, 0);
        o1 = __builtin_amdgcn_mfma_f32_32x32x16_bf16(vb[2], pb0.v, o1, 0, 0, 0);
        o0 = __builtin_amdgcn_mfma_f32_32x32x16_bf16(va[3], pb1.v, o0, 0, 0, 0);
        o1 = __builtin_amdgcn_mfma_f32_32x32x16_bf16(vb[3], pb1.v, o1, 0, 0, 0);
        __builtin_amdgcn_s_setprio(0);
    }

    if (nW & 1) {   // tail single tile
        const int t = w1 - 1;
        const int n0 = t * 32;
        const unsigned short* Kr = K + (size_t)(n0 + col) * DIM + hi * 8;
        bf16x8 kA[4];
        #pragma unroll
        for (int ks = 0; ks < 4; ++ks) kA[ks] = *(const bf16x8*)(Kr + ks * 16);
        const unsigned short* Vr0 = Vt + (size_t)col * SEQ + n0 + hi * 8;
        const unsigned short* Vr1 = Vr0 + 32 * SEQ;
        bf16x8 va0 = *(const bf16x8*)(Vr0);
        bf16x8 va1 = *(const bf16x8*)(Vr0 + 16);
        bf16x8 vb0 = *(const bf16x8*)(Vr1);
        bf16x8 vb1 = *(const bf16x8*)(Vr1 + 16);

        f32x16 sa;
        #pragma unroll
        for (int r = 0; r < 16; ++r) sa[r] = 0.f;
        __builtin_amdgcn_s_setprio(1);
        #pragma unroll
        for (int ks = 0; ks < 4; ++ks)
            sa = __builtin_amdgcn_mfma_f32_32x32x16_bf16(kA[ks], qf[ks], sa, 0, 0, 0);
        __builtin_amdgcn_s_setprio(0);

        float p0[16];
        #pragma unroll
        for (int r = 0; r < 16; ++r) p0[r] = sa[r] * SCL;
        if (t == qt) {
            #pragma unroll
            for (int r = 0; r < 16; ++r) {
                const int kvr = (r & 3) + 8 * (r >> 2) + 4 * hi;
                if (kvr > col) p0[r] = -1e30f;
            }
        }
        float tm = p0[0];
        #pragma unroll
        for (int r = 1; r < 16; ++r) tm = fmaxf(tm, p0[r]);
        tm = fmaxf(tm, __shfl_xor(tm, 32));
        if (!__all(tm <= m_i + 2.0f)) {
            const float mn = fmaxf(m_i, tm);
            const float alpha = EXP2(m_i - mn);
            m_i = mn;
            l_i *= alpha;
            #pragma unroll
            for (int r = 0; r < 16; ++r) { o0[r] *= alpha; o1[r] *= alpha; }
        }
        float rs = 0.f;
        #pragma unroll
        for (int r = 0; r < 16; ++r) { p0[r] = EXP2(p0[r] - m_i); rs += p0[r]; }
        rs += __shfl_xor(rs, 32);
        l_i += rs;

        unsigned pwA[8];
        #pragma unroll
        for (int i = 0; i < 8; ++i) pwA[i] = cvtpk(p0[2 * i], p0[2 * i + 1]);
        asm volatile("v_permlane32_swap_b32 %0, %1" : "+v"(pwA[0]), "+v"(pwA[2]));
        asm volatile("v_permlane32_swap_b32 %0, %1" : "+v"(pwA[1]), "+v"(pwA[3]));
        asm volatile("v_permlane32_swap_b32 %0, %1" : "+v"(pwA[4]), "+v"(pwA[6]));
        asm volatile("v_permlane32_swap_b32 %0, %1" : "+v"(pwA[5]), "+v"(pwA[7]));
        union { unsigned uu[4]; bf16x8 v; } pa0, pa1;
        pa0.uu[0] = pwA[0]; pa0.uu[1] = pwA[1]; pa0.uu[2] = pwA[2]; pa0.uu[3] = pwA[3];
        pa1.uu[0] = pwA[4]; pa1.uu[1] = pwA[5]; pa1.uu[2] = pwA[6]; pa1.uu[3] = pwA[7];

        __builtin_amdgcn_s_setprio(1);
        o0 = __builtin_amdgcn_mfma_f32_32x32x16_bf16(va0, pa0.v, o0, 0, 0, 0);
        o1 = __builtin_amdgcn_mfma_f32_32x32x16_bf16(vb0, pa0.v, o1, 0, 0, 0);
        o0 = __builtin_amdgcn_mfma_f32_32x32x16_bf16(va1, pa1.v, o0, 0, 0, 0);
        o1 = __builtin_amdgcn_mfma_f32_32x32x16_bf16(vb1, pa1.v, o1, 0, 0, 0);
        __builtin_amdgcn_s_setprio(0);
    }

    // per-wave partial -> LDS (O^T: lane col = q, regs = d)
    #pragma unroll
    for (int r = 0; r < 16; ++r) {
        const int d = (r & 3) + 8 * (r >> 2) + 4 * hi;
        Oall[w][col][d]      = o0[r];
        Oall[w][col][32 + d] = o1[r];
    }
    if (hi == 0) { Ml[w][col][0] = m_i; Ml[w][col][1] = l_i; }
    __syncthreads();

    if (tid < 32) {
        float M = Ml[0][tid][0];
        #pragma unroll
        for (int w2 = 1; w2 < 4; ++w2) M = fmaxf(M, Ml[w2][tid][0]);
        sM[tid] = M;
    }
    __syncthreads();
    if (tid < 128) {
        const int w2 = tid >> 5, r = tid & 31;
        sScl[w2][r] = EXP2(Ml[w2][r][0] - sM[r]);
    }
    __syncthreads();
    if (tid < 32) {
        float L = 0.f;
        #pragma unroll
        for (int w2 = 0; w2 < 4; ++w2) L += Ml[w2][tid][1] * sScl[w2][tid];
        sL[tid] = L;
    }
    __syncthreads();

    const int r = tid >> 3;
    const int c0 = (tid & 7) * 8;
    f32x4 a0 = (f32x4){0.f, 0.f, 0.f, 0.f};
    f32x4 a1 = (f32x4){0.f, 0.f, 0.f, 0.f};
    #pragma unroll
    for (int w2 = 0; w2 < 4; ++w2) {
        const float sc = sScl[w2][r];
        const float* Orow = &Oall[w2][r][c0];
        a0 += (*(const f32x4*)(Orow)) * sc;
        a1 += (*(const f32x4*)(Orow + 4)) * sc;
    }
    if (qt < 32) {   // single chunk: write final output
        const float inv = 1.f / sL[r];
        float* op = out + (size_t)(m0 + r) * DIM + c0;
        *(f32x4*)(op)     = a0 * inv;
        *(f32x4*)(op + 4) = a1 * inv;
    } else {         // write partial for fixup
        const int pb = 16 * (g - 1) * (g + 2) + (qt - 32 * g) * (g + 1) + cid;
        float* op = Opart + (size_t)pb * 2048 + r * 64 + c0;
        *(f32x4*)(op)     = a0;
        *(f32x4*)(op + 4) = a1;
        if (tid < 32) {
            MLpart[(size_t)pb * 64 + tid * 2]     = sM[tid];
            MLpart[(size_t)pb * 64 + tid * 2 + 1] = sL[tid];
        }
    }
}

// ---- Fixup: merge chunk partials for qt >= 32. 224 blocks x 256 ------------
__global__ __launch_bounds__(256) void fixup_kernel(
    const float* __restrict__ Opart, const float* __restrict__ MLpart,
    float* __restrict__ out)
{
    __shared__ float sScl[8][32];
    __shared__ float sInvL[32];

    const int qt = 32 + (int)blockIdx.x;
    const int g  = qt >> 5;
    const int nc = g + 1;
    const int pb = 16 * (g - 1) * (g + 2) + (qt - 32 * g) * nc;
    const int tid = (int)threadIdx.x;

    if (tid < 32) {
        float M = -1e30f;
        for (int c2 = 0; c2 < nc; ++c2)
            M = fmaxf(M, MLpart[(size_t)(pb + c2) * 64 + tid * 2]);
        float L = 0.f;
        for (int c2 = 0; c2 < nc; ++c2) {
            const float sc = EXP2(MLpart[(size_t)(pb + c2) * 64 + tid * 2] - M);
            sScl[c2][tid] = sc;
            L += MLpart[(size_t)(pb + c2) * 64 + tid * 2 + 1] * sc;
        }
        sInvL[tid] = 1.f / L;
    }
    __syncthreads();

    const int r = tid >> 3;
    const int c0 = (tid & 7) * 8;
    f32x4 a0 = (f32x4){0.f, 0.f, 0.f, 0.f};
    f32x4 a1 = (f32x4){0.f, 0.f, 0.f, 0.f};
    for (int c2 = 0; c2 < nc; ++c2) {
        const float sc = sScl[c2][r];
        const float* Op = Opart + (size_t)(pb + c2) * 2048 + r * 64 + c0;
        a0 += (*(const f32x4*)(Op)) * sc;
        a1 += (*(const f32x4*)(Op + 4)) * sc;
    }
    const float inv = sInvL[r];
    float* op = out + (size_t)(qt * 32 + r) * DIM + c0;
    *(f32x4*)(op)     = a0 * inv;
    *(f32x4*)(op + 4) = a1 * inv;
}

extern "C" void kernel_launch(void* const* d_in, const int* in_sizes, int n_in,
                              void* d_out, int out_size, void* d_ws, size_t ws_size,
                              hipStream_t stream) {
    const float* x  = (const float*)d_in[0];
    const float* y  = (const float*)d_in[1];
    const float* z  = (const float*)d_in[2];
    const float* Wq = (const float*)d_in[3];
    const float* bq = (const float*)d_in[4];
    const float* Wk = (const float*)d_in[5];
    const float* bk = (const float*)d_in[6];
    const float* Wv = (const float*)d_in[7];
    const float* bv = (const float*)d_in[8];

    unsigned short* qkv = (unsigned short*)d_ws;
    unsigned short* Wt  = (unsigned short*)((char*)d_ws + 3145728);
    float* Opart        = (float*)((char*)d_ws + 3538944);
    float* MLpart       = (float*)((char*)d_ws + 12713984);
    float* out          = (float*)d_out;

    hipLaunchKernelGGL(wt_kernel,    dim3(192),  dim3(256), 0, stream, Wq, Wk, Wv, Wt);
    hipLaunchKernelGGL(proj_kernel,  dim3(768),  dim3(512), 0, stream, x, y, z, bq, bk, bv, Wt, qkv);
    hipLaunchKernelGGL(attn_kernel,  dim3(1152), dim3(256), 0, stream, qkv, out, Opart, MLpart);
    hipLaunchKernelGGL(fixup_kernel, dim3(224),  dim3(256), 0, stream, Opart, MLpart, out);
}

// Round 6
// 71.940 us; speedup vs baseline: 2.0698x; 1.2138x over previous
//
#include <hip/hip_runtime.h>

#define SEQ 8192
#define EMB 1024
#define DIM 64

typedef __attribute__((ext_vector_type(8))) short bf16x8;
typedef __attribute__((ext_vector_type(4))) float f32x4;
typedef __attribute__((ext_vector_type(16))) float f32x16;

#if __has_builtin(__builtin_amdgcn_exp2f)
#define EXP2 __builtin_amdgcn_exp2f
#else
#define EXP2 exp2f
#endif

// softmax scale folded with log2(e): (1/sqrt(8192)) * 1.4426950408889634
#define SCL 0.0159396779f

__device__ inline unsigned short f2bf(float f) {
    union { float f; unsigned u; } x; x.f = f;
    unsigned r = x.u + 0x7FFFu + ((x.u >> 16) & 1u);
    return (unsigned short)(r >> 16);
}

__device__ inline unsigned cvtpk(float lo, float hi) {
    unsigned r;
    asm("v_cvt_pk_bf16_f32 %0, %1, %2" : "=v"(r) : "v"(lo), "v"(hi));
    return r;
}

__device__ __forceinline__ void gload16(const float* g, float* l) {
    __builtin_amdgcn_global_load_lds(
        (const __attribute__((address_space(1))) unsigned*)g,
        (__attribute__((address_space(3))) unsigned*)l, 16, 0, 0);
}

// ---------------------------------------------------------------------------
// ws layout (bytes):
//  qkv @ 0        : q[8192][64] row-major | KF fragment | VF fragment  bf16
//  WF  @ 3145728  : [3][32 sg][4 wc][64 lane][8] bf16 fragment layout (393,216)
//  Opart @ 3538944, MLpart @ 12713984
//
// KF elem ((t*4+ks)*2+hi)*256 + col*8 + j  = K[t*32+col][ks*16+hi*8+j]
// VF elem ((t*2+i)*2+h)*512 + (hi*32+col)*8 + j = V[t*32+i*16+hi*8+j][h*32+col]
// WF elem (((mat*32+sg)*4+wc)*64 + qq*16+c)*8 + j = W[sg*32+qq*8+j][wc*16+c]
// ---------------------------------------------------------------------------

// ---- W -> bf16 fragment layout --------------------------------------------
__global__ __launch_bounds__(256) void wt_kernel(
    const float* __restrict__ Wq, const float* __restrict__ Wk,
    const float* __restrict__ Wv, unsigned short* __restrict__ Wt)
{
    const int f = (int)blockIdx.x * 256 + (int)threadIdx.x;  // 49152 threads
    const int n    = f & 63;
    const int rest = f >> 6;
    const int mat  = rest >> 8;
    const int kp   = (rest & 255) * 4;      // k base (multiple of 4)
    const float* W = (mat == 0) ? Wq : (mat == 1) ? Wk : Wv;
    const int sg = kp >> 5, qq = (kp >> 3) & 3, j0 = kp & 7;   // j0 in {0,4}
    const int wcg = n >> 4, c = n & 15;
    const int lanep = qq * 16 + c;
    float v0 = W[(size_t)(kp + 0) * DIM + n];
    float v1 = W[(size_t)(kp + 1) * DIM + n];
    float v2 = W[(size_t)(kp + 2) * DIM + n];
    float v3 = W[(size_t)(kp + 3) * DIM + n];
    uint2 pk;
    pk.x = cvtpk(v0, v1);
    pk.y = cvtpk(v2, v3);
    const size_t off = ((size_t)(((mat * 32 + sg) * 4 + wcg)) * 64 + lanep) * 8 + j0;
    *(uint2*)&Wt[off] = pk;
}

__device__ inline bf16x8 cvt8(float4 a, float4 b) {
    union { unsigned u[4]; bf16x8 v; } r;
    r.u[0] = cvtpk(a.x, a.y);
    r.u[1] = cvtpk(a.z, a.w);
    r.u[2] = cvtpk(b.x, b.y);
    r.u[3] = cvtpk(b.z, b.w);
    return r.v;
}

// ---- Projection: gload_lds X staging + fragment W; K swapped -> KF, V -> VF
// 768 blocks x 512 thr (8 waves). Block = 32 rows x 64 cols; K tiled at 256.
__global__ __launch_bounds__(512) void proj_kernel(
    const float* __restrict__ x, const float* __restrict__ y, const float* __restrict__ z,
    const float* __restrict__ bq, const float* __restrict__ bk, const float* __restrict__ bv,
    const unsigned short* __restrict__ Wt, unsigned short* __restrict__ qkv)
{
    __shared__ float tile[2][32][256];

    const int bid = (int)blockIdx.x;
    const int mat = bid >> 8;                 // 0=q,1=k,2=v (256 blocks each)
    const int rb  = (bid & 255) * 32;

    const int tid  = (int)threadIdx.x;
    const int lane = tid & 63;
    const int w    = tid >> 6;                // 0..7
    const int wr   = w >> 2;                  // row-tile 0..1
    const int wc   = w & 3;                   // col-tile 0..3
    const int c    = lane & 15;
    const int qq   = lane >> 4;

    const float* X  = (mat == 0) ? x  : (mat == 1) ? y  : z;
    const float* Bv = (mat == 0) ? bq : (mat == 1) ? bk : bv;
    const unsigned short* Wm = Wt + (size_t)mat * 65536;
    unsigned short* outp = qkv + (size_t)mat * (SEQ * DIM);

    f32x4 acc = (f32x4){0.f, 0.f, 0.f, 0.f};

    const int arow = wr * 16 + c;             // A-fragment LDS row
    const int sw   = (c & 7) << 4;            // read-side XOR (bytes)
    const char* rbf0 = (const char*)&tile[0][arow][0];
    const char* rbf1 = (const char*)&tile[1][arow][0];
    const unsigned short* Wp = Wm + (size_t)wc * 512 + (size_t)lane * 8;
    const bool swapped = (mat == 1);

    #define STAGE(nb, t)                                                        \
        {                                                                       \
            const int k0_ = (t) * 256;                                          \
            _Pragma("unroll")                                                   \
            for (int j = 0; j < 4; ++j) {                                       \
                const int r_ = w * 4 + j;                                       \
                const float* src_ = X + (size_t)(rb + r_) * EMB + k0_           \
                                      + ((lane ^ (r_ & 7)) << 2);               \
                gload16(src_, &tile[nb][r_][0]);                                \
            }                                                                   \
        }

    STAGE(0, 0);
    __syncthreads();

    int buf = 0;
    #pragma unroll
    for (int t = 0; t < 4; ++t) {
        if (t < 3) STAGE(buf ^ 1, t + 1);
        const char* rowb = buf ? rbf1 : rbf0;
        #pragma unroll
        for (int s = 0; s < 8; ++s) {
            const int base = s * 128 + qq * 32;
            float4 fa = *(const float4*)(rowb + ((base) ^ sw));
            float4 fb = *(const float4*)(rowb + ((base + 16) ^ sw));
            bf16x8 af = cvt8(fa, fb);
            bf16x8 bfr = *(const bf16x8*)(Wp + (size_t)(t * 8 + s) * 2048);
            if (swapped)
                acc = __builtin_amdgcn_mfma_f32_16x16x32_bf16(bfr, af, acc, 0, 0, 0);
            else
                acc = __builtin_amdgcn_mfma_f32_16x16x32_bf16(af, bfr, acc, 0, 0, 0);
        }
        __syncthreads();
        buf ^= 1;
    }
    #undef STAGE

    const int T = rb >> 5;
    if (mat == 0) {
        const int col = wc * 16 + c;
        const float bb = Bv[col];
        #pragma unroll
        for (int i = 0; i < 4; ++i) {
            const int row = rb + wr * 16 + qq * 4 + i;
            outp[(size_t)row * DIM + col] = f2bf(acc[i] + bb);
        }
    } else if (mat == 1) {   // KF: thread holds K^T (d = wc*16+qq*4+ii, kv = rb+wr*16+c)
        f32x4 bb4 = *(const f32x4*)&Bv[wc * 16 + qq * 4];
        const int base = (((T * 4 + wc) * 2 + (qq >> 1)) * 32 + wr * 16 + c) * 8 + (qq & 1) * 4;
        uint2 pk;
        pk.x = cvtpk(acc[0] + bb4[0], acc[1] + bb4[1]);
        pk.y = cvtpk(acc[2] + bb4[2], acc[3] + bb4[3]);
        *(uint2*)&outp[base] = pk;
    } else {                 // VF: thread holds V (kv = rb+wr*16+qq*4+ii, d = wc*16+c)
        const float bb = Bv[wc * 16 + c];
        const int base = ((((T * 2 + wr) * 2 + (wc >> 1)) * 2 + (qq >> 1)) * 32
                          + (wc & 1) * 16 + c) * 8 + (qq & 1) * 4;
        uint2 pk;
        pk.x = cvtpk(acc[0] + bb, acc[1] + bb);
        pk.y = cvtpk(acc[2] + bb, acc[3] + bb);
        *(uint2*)&outp[base] = pk;
    }
}

// ---- Flash attention: swapped-operand 32x32, KVBLK=64 pairs, defer-max -----
// 1152 blocks x 256 thr (4 waves). Unit = (qtile, 32-tile KV chunk).
// K/V read from fragment layouts: every load is base + lane*16B (coalesced).
__global__ __launch_bounds__(256, 3) void attn_kernel(
    const unsigned short* __restrict__ qkv, float* __restrict__ out,
    float* __restrict__ Opart, float* __restrict__ MLpart)
{
    const unsigned short* Q  = qkv;
    const unsigned short* KF = qkv + SEQ * DIM;
    const unsigned short* VF = qkv + 2 * SEQ * DIM;

    __shared__ float Oall[4][32][68];
    __shared__ float Ml[4][32][2];
    __shared__ float sScl[4][32];
    __shared__ float sM[32];
    __shared__ float sL[32];

    // unit id, longest-first
    const int u = 1151 - (int)blockIdx.x;
    int g;
    if (u < 32) g = 0; else if (u < 96) g = 1; else if (u < 192) g = 2;
    else if (u < 320) g = 3; else if (u < 480) g = 4; else if (u < 672) g = 5;
    else if (u < 896) g = 6; else g = 7;
    const int o_  = u - 16 * g * (g + 1);
    const int qt  = 32 * g + o_ / (g + 1);
    const int cid = o_ - (o_ / (g + 1)) * (g + 1);

    const int m0 = qt * 32;
    const int tid = (int)threadIdx.x;
    const int lane = tid & 63;
    const int w = tid >> 6;        // 0..3
    const int col = lane & 31;     // q row within tile
    const int hi = lane >> 5;

    // Q fragments (B-operand) — strided but read once per block
    bf16x8 qf[4];
    {
        const unsigned short* Qr = Q + (size_t)(m0 + col) * DIM + hi * 8;
        #pragma unroll
        for (int ks = 0; ks < 4; ++ks) qf[ks] = *(const bf16x8*)(Qr + ks * 16);
    }

    f32x16 o0, o1;
    #pragma unroll
    for (int r = 0; r < 16; ++r) { o0[r] = 0.f; o1[r] = 0.f; }
    float m_i = -1e30f, l_i = 0.f;

    const int nT = qt + 1;
    const int tb = cid * 32;
    const int te = (tb + 32 < nT) ? (tb + 32) : nT;
    const int nC = te - tb;
    const int w0 = tb + ((nC * w) >> 2);
    const int w1 = tb + ((nC * (w + 1)) >> 2);
    const int nW = w1 - w0;
    const int nP = nW >> 1;

    for (int pi = 0; pi < nP; ++pi) {
        const int t = w0 + 2 * pi;
        // ---- coalesced fragment loads: K pair + V pair ----
        const unsigned short* kb = KF + (size_t)t * 2048 + (size_t)lane * 8;
        const unsigned short* vb_ = VF + (size_t)t * 2048 + (size_t)lane * 8;
        bf16x8 kA[4], kB[4];
        #pragma unroll
        for (int ks = 0; ks < 4; ++ks) kA[ks] = *(const bf16x8*)(kb + ks * 512);
        #pragma unroll
        for (int ks = 0; ks < 4; ++ks) kB[ks] = *(const bf16x8*)(kb + 2048 + ks * 512);
        bf16x8 va[4], vbf[4];
        #pragma unroll
        for (int i = 0; i < 4; ++i) va[i]  = *(const bf16x8*)(vb_ + i * 1024);
        #pragma unroll
        for (int i = 0; i < 4; ++i) vbf[i] = *(const bf16x8*)(vb_ + 512 + i * 1024);

        // ---- dual QK chains ----
        f32x16 sa, sb;
        #pragma unroll
        for (int r = 0; r < 16; ++r) { sa[r] = 0.f; sb[r] = 0.f; }
        __builtin_amdgcn_s_setprio(1);
        #pragma unroll
        for (int ks = 0; ks < 4; ++ks) {
            sa = __builtin_amdgcn_mfma_f32_32x32x16_bf16(kA[ks], qf[ks], sa, 0, 0, 0);
            sb = __builtin_amdgcn_mfma_f32_32x32x16_bf16(kB[ks], qf[ks], sb, 0, 0, 0);
        }
        __builtin_amdgcn_s_setprio(0);

        float p0[16], p1[16];
        #pragma unroll
        for (int r = 0; r < 16; ++r) { p0[r] = sa[r] * SCL; p1[r] = sb[r] * SCL; }
        if (t + 1 == qt) {   // diagonal can only be the second tile of a pair
            #pragma unroll
            for (int r = 0; r < 16; ++r) {
                const int kvr = (r & 3) + 8 * (r >> 2) + 4 * hi;
                if (kvr > col) p1[r] = -1e30f;
            }
        }
        float tm = fmaxf(p0[0], p1[0]);
        #pragma unroll
        for (int r = 1; r < 16; ++r) tm = fmaxf(tm, fmaxf(p0[r], p1[r]));
        tm = fmaxf(tm, __shfl_xor(tm, 32));
        if (!__all(tm <= m_i + 2.0f)) {
            const float mn = fmaxf(m_i, tm);
            const float alpha = EXP2(m_i - mn);
            m_i = mn;
            l_i *= alpha;
            #pragma unroll
            for (int r = 0; r < 16; ++r) { o0[r] *= alpha; o1[r] *= alpha; }
        }
        float rs = 0.f;
        #pragma unroll
        for (int r = 0; r < 16; ++r) { p0[r] = EXP2(p0[r] - m_i); rs += p0[r]; }
        #pragma unroll
        for (int r = 0; r < 16; ++r) { p1[r] = EXP2(p1[r] - m_i); rs += p1[r]; }
        rs += __shfl_xor(rs, 32);
        l_i += rs;

        unsigned pwA[8], pwB[8];
        #pragma unroll
        for (int i = 0; i < 8; ++i) pwA[i] = cvtpk(p0[2 * i], p0[2 * i + 1]);
        #pragma unroll
        for (int i = 0; i < 8; ++i) pwB[i] = cvtpk(p1[2 * i], p1[2 * i + 1]);
        asm volatile("v_permlane32_swap_b32 %0, %1" : "+v"(pwA[0]), "+v"(pwA[2]));
        asm volatile("v_permlane32_swap_b32 %0, %1" : "+v"(pwA[1]), "+v"(pwA[3]));
        asm volatile("v_permlane32_swap_b32 %0, %1" : "+v"(pwA[4]), "+v"(pwA[6]));
        asm volatile("v_permlane32_swap_b32 %0, %1" : "+v"(pwA[5]), "+v"(pwA[7]));
        asm volatile("v_permlane32_swap_b32 %0, %1" : "+v"(pwB[0]), "+v"(pwB[2]));
        asm volatile("v_permlane32_swap_b32 %0, %1" : "+v"(pwB[1]), "+v"(pwB[3]));
        asm volatile("v_permlane32_swap_b32 %0, %1" : "+v"(pwB[4]), "+v"(pwB[6]));
        asm volatile("v_permlane32_swap_b32 %0, %1" : "+v"(pwB[5]), "+v"(pwB[7]));
        union { unsigned uu[4]; bf16x8 v; } pa0, pa1, pb0, pb1;
        pa0.uu[0] = pwA[0]; pa0.uu[1] = pwA[1]; pa0.uu[2] = pwA[2]; pa0.uu[3] = pwA[3];
        pa1.uu[0] = pwA[4]; pa1.uu[1] = pwA[5]; pa1.uu[2] = pwA[6]; pa1.uu[3] = pwA[7];
        pb0.uu[0] = pwB[0]; pb0.uu[1] = pwB[1]; pb0.uu[2] = pwB[2]; pb0.uu[3] = pwB[3];
        pb1.uu[0] = pwB[4]; pb1.uu[1] = pwB[5]; pb1.uu[2] = pwB[6]; pb1.uu[3] = pwB[7];

        __builtin_amdgcn_s_setprio(1);
        o0 = __builtin_amdgcn_mfma_f32_32x32x16_bf16(va[0],  pa0.v, o0, 0, 0, 0);
        o1 = __builtin_amdgcn_mfma_f32_32x32x16_bf16(vbf[0], pa0.v, o1, 0, 0, 0);
        o0 = __builtin_amdgcn_mfma_f32_32x32x16_bf16(va[1],  pa1.v, o0, 0, 0, 0);
        o1 = __builtin_amdgcn_mfma_f32_32x32x16_bf16(vbf[1], pa1.v, o1, 0, 0, 0);
        o0 = __builtin_amdgcn_mfma_f32_32x32x16_bf16(va[2],  pb0.v, o0, 0, 0, 0);
        o1 = __builtin_amdgcn_mfma_f32_32x32x16_bf16(vbf[2], pb0.v, o1, 0, 0, 0);
        o0 = __builtin_amdgcn_mfma_f32_32x32x16_bf16(va[3],  pb1.v, o0, 0, 0, 0);
        o1 = __builtin_amdgcn_mfma_f32_32x32x16_bf16(vbf[3], pb1.v, o1, 0, 0, 0);
        __builtin_amdgcn_s_setprio(0);
    }

    if (nW & 1) {   // tail single tile
        const int t = w1 - 1;
        const unsigned short* kb = KF + (size_t)t * 2048 + (size_t)lane * 8;
        const unsigned short* vb_ = VF + (size_t)t * 2048 + (size_t)lane * 8;
        bf16x8 kA[4];
        #pragma unroll
        for (int ks = 0; ks < 4; ++ks) kA[ks] = *(const bf16x8*)(kb + ks * 512);
        bf16x8 va0 = *(const bf16x8*)(vb_);
        bf16x8 va1 = *(const bf16x8*)(vb_ + 1024);
        bf16x8 vb0 = *(const bf16x8*)(vb_ + 512);
        bf16x8 vb1 = *(const bf16x8*)(vb_ + 1536);

        f32x16 sa;
        #pragma unroll
        for (int r = 0; r < 16; ++r) sa[r] = 0.f;
        __builtin_amdgcn_s_setprio(1);
        #pragma unroll
        for (int ks = 0; ks < 4; ++ks)
            sa = __builtin_amdgcn_mfma_f32_32x32x16_bf16(kA[ks], qf[ks], sa, 0, 0, 0);
        __builtin_amdgcn_s_setprio(0);

        float p0[16];
        #pragma unroll
        for (int r = 0; r < 16; ++r) p0[r] = sa[r] * SCL;
        if (t == qt) {
            #pragma unroll
            for (int r = 0; r < 16; ++r) {
                const int kvr = (r & 3) + 8 * (r >> 2) + 4 * hi;
                if (kvr > col) p0[r] = -1e30f;
            }
        }
        float tm = p0[0];
        #pragma unroll
        for (int r = 1; r < 16; ++r) tm = fmaxf(tm, p0[r]);
        tm = fmaxf(tm, __shfl_xor(tm, 32));
        if (!__all(tm <= m_i + 2.0f)) {
            const float mn = fmaxf(m_i, tm);
            const float alpha = EXP2(m_i - mn);
            m_i = mn;
            l_i *= alpha;
            #pragma unroll
            for (int r = 0; r < 16; ++r) { o0[r] *= alpha; o1[r] *= alpha; }
        }
        float rs = 0.f;
        #pragma unroll
        for (int r = 0; r < 16; ++r) { p0[r] = EXP2(p0[r] - m_i); rs += p0[r]; }
        rs += __shfl_xor(rs, 32);
        l_i += rs;

        unsigned pwA[8];
        #pragma unroll
        for (int i = 0; i < 8; ++i) pwA[i] = cvtpk(p0[2 * i], p0[2 * i + 1]);
        asm volatile("v_permlane32_swap_b32 %0, %1" : "+v"(pwA[0]), "+v"(pwA[2]));
        asm volatile("v_permlane32_swap_b32 %0, %1" : "+v"(pwA[1]), "+v"(pwA[3]));
        asm volatile("v_permlane32_swap_b32 %0, %1" : "+v"(pwA[4]), "+v"(pwA[6]));
        asm volatile("v_permlane32_swap_b32 %0, %1" : "+v"(pwA[5]), "+v"(pwA[7]));
        union { unsigned uu[4]; bf16x8 v; } pa0, pa1;
        pa0.uu[0] = pwA[0]; pa0.uu[1] = pwA[1]; pa0.uu[2] = pwA[2]; pa0.uu[3] = pwA[3];
        pa1.uu[0] = pwA[4]; pa1.uu[1] = pwA[5]; pa1.uu[2] = pwA[6]; pa1.uu[3] = pwA[7];

        __builtin_amdgcn_s_setprio(1);
        o0 = __builtin_amdgcn_mfma_f32_32x32x16_bf16(va0, pa0.v, o0, 0, 0, 0);
        o1 = __builtin_amdgcn_mfma_f32_32x32x16_bf16(vb0, pa0.v, o1, 0, 0, 0);
        o0 = __builtin_amdgcn_mfma_f32_32x32x16_bf16(va1, pa1.v, o0, 0, 0, 0);
        o1 = __builtin_amdgcn_mfma_f32_32x32x16_bf16(vb1, pa1.v, o1, 0, 0, 0);
        __builtin_amdgcn_s_setprio(0);
    }

    // per-wave partial -> LDS (O^T: lane col = q, regs = d)
    #pragma unroll
    for (int r = 0; r < 16; ++r) {
        const int d = (r & 3) + 8 * (r >> 2) + 4 * hi;
        Oall[w][col][d]      = o0[r];
        Oall[w][col][32 + d] = o1[r];
    }
    if (hi == 0) { Ml[w][col][0] = m_i; Ml[w][col][1] = l_i; }
    __syncthreads();

    if (tid < 32) {
        float M = Ml[0][tid][0];
        #pragma unroll
        for (int w2 = 1; w2 < 4; ++w2) M = fmaxf(M, Ml[w2][tid][0]);
        sM[tid] = M;
    }
    __syncthreads();
    if (tid < 128) {
        const int w2 = tid >> 5, r = tid & 31;
        sScl[w2][r] = EXP2(Ml[w2][r][0] - sM[r]);
    }
    __syncthreads();
    if (tid < 32) {
        float L = 0.f;
        #pragma unroll
        for (int w2 = 0; w2 < 4; ++w2) L += Ml[w2][tid][1] * sScl[w2][tid];
        sL[tid] = L;
    }
    __syncthreads();

    const int r = tid >> 3;
    const int c0 = (tid & 7) * 8;
    f32x4 a0 = (f32x4){0.f, 0.f, 0.f, 0.f};
    f32x4 a1 = (f32x4){0.f, 0.f, 0.f, 0.f};
    #pragma unroll
    for (int w2 = 0; w2 < 4; ++w2) {
        const float sc = sScl[w2][r];
        const float* Orow = &Oall[w2][r][c0];
        a0 += (*(const f32x4*)(Orow)) * sc;
        a1 += (*(const f32x4*)(Orow + 4)) * sc;
    }
    if (qt < 32) {
        const float inv = 1.f / sL[r];
        float* op = out + (size_t)(m0 + r) * DIM + c0;
        *(f32x4*)(op)     = a0 * inv;
        *(f32x4*)(op + 4) = a1 * inv;
    } else {
        const int pb = 16 * (g - 1) * (g + 2) + (qt - 32 * g) * (g + 1) + cid;
        float* op = Opart + (size_t)pb * 2048 + r * 64 + c0;
        *(f32x4*)(op)     = a0;
        *(f32x4*)(op + 4) = a1;
        if (tid < 32) {
            MLpart[(size_t)pb * 64 + tid * 2]     = sM[tid];
            MLpart[(size_t)pb * 64 + tid * 2 + 1] = sL[tid];
        }
    }
}

// ---- Fixup: merge chunk partials for qt >= 32. 224 blocks x 256 ------------
__global__ __launch_bounds__(256) void fixup_kernel(
    const float* __restrict__ Opart, const float* __restrict__ MLpart,
    float* __restrict__ out)
{
    __shared__ float sScl[8][32];
    __shared__ float sInvL[32];

    const int qt = 32 + (int)blockIdx.x;
    const int g  = qt >> 5;
    const int nc = g + 1;
    const int pb = 16 * (g - 1) * (g + 2) + (qt - 32 * g) * nc;
    const int tid = (int)threadIdx.x;

    if (tid < 32) {
        float M = -1e30f;
        for (int c2 = 0; c2 < nc; ++c2)
            M = fmaxf(M, MLpart[(size_t)(pb + c2) * 64 + tid * 2]);
        float L = 0.f;
        for (int c2 = 0; c2 < nc; ++c2) {
            const float sc = EXP2(MLpart[(size_t)(pb + c2) * 64 + tid * 2] - M);
            sScl[c2][tid] = sc;
            L += MLpart[(size_t)(pb + c2) * 64 + tid * 2 + 1] * sc;
        }
        sInvL[tid] = 1.f / L;
    }
    __syncthreads();

    const int r = tid >> 3;
    const int c0 = (tid & 7) * 8;
    f32x4 a0 = (f32x4){0.f, 0.f, 0.f, 0.f};
    f32x4 a1 = (f32x4){0.f, 0.f, 0.f, 0.f};
    for (int c2 = 0; c2 < nc; ++c2) {
        const float sc = sScl[c2][r];
        const float* Op = Opart + (size_t)(pb + c2) * 2048 + r * 64 + c0;
        a0 += (*(const f32x4*)(Op)) * sc;
        a1 += (*(const f32x4*)(Op + 4)) * sc;
    }
    const float inv = sInvL[r];
    float* op = out + (size_t)(qt * 32 + r) * DIM + c0;
    *(f32x4*)(op)     = a0 * inv;
    *(f32x4*)(op + 4) = a1 * inv;
}

extern "C" void kernel_launch(void* const* d_in, const int* in_sizes, int n_in,
                              void* d_out, int out_size, void* d_ws, size_t ws_size,
                              hipStream_t stream) {
    const float* x  = (const float*)d_in[0];
    const float* y  = (const float*)d_in[1];
    const float* z  = (const float*)d_in[2];
    const float* Wq = (const float*)d_in[3];
    const float* bq = (const float*)d_in[4];
    const float* Wk = (const float*)d_in[5];
    const float* bk = (const float*)d_in[6];
    const float* Wv = (const float*)d_in[7];
    const float* bv = (const float*)d_in[8];

    unsigned short* qkv = (unsigned short*)d_ws;
    unsigned short* Wt  = (unsigned short*)((char*)d_ws + 3145728);
    float* Opart        = (float*)((char*)d_ws + 3538944);
    float* MLpart       = (float*)((char*)d_ws + 12713984);
    float* out          = (float*)d_out;

    hipLaunchKernelGGL(wt_kernel,    dim3(192),  dim3(256), 0, stream, Wq, Wk, Wv, Wt);
    hipLaunchKernelGGL(proj_kernel,  dim3(768),  dim3(512), 0, stream, x, y, z, bq, bk, bv, Wt, qkv);
    hipLaunchKernelGGL(attn_kernel,  dim3(1152), dim3(256), 0, stream, qkv, out, Opart, MLpart);
    hipLaunchKernelGGL(fixup_kernel, dim3(224),  dim3(256), 0, stream, Opart, MLpart, out);
}

// Round 7
// 59.988 us; speedup vs baseline: 2.4823x; 1.1992x over previous
//
#include <hip/hip_runtime.h>

#define SEQ 8192
#define EMB 1024
#define DIM 64

typedef __attribute__((ext_vector_type(8))) short bf16x8;
typedef __attribute__((ext_vector_type(4))) float f32x4;
typedef __attribute__((ext_vector_type(16))) float f32x16;

#if __has_builtin(__builtin_amdgcn_exp2f)
#define EXP2 __builtin_amdgcn_exp2f
#else
#define EXP2 exp2f
#endif

// softmax scale folded with log2(e): (1/sqrt(8192)) * 1.4426950408889634
#define SCL 0.0159396779f

__device__ inline unsigned short f2bf(float f) {
    union { float f; unsigned u; } x; x.f = f;
    unsigned r = x.u + 0x7FFFu + ((x.u >> 16) & 1u);
    return (unsigned short)(r >> 16);
}

__device__ inline unsigned cvtpk(float lo, float hi) {
    unsigned r;
    asm("v_cvt_pk_bf16_f32 %0, %1, %2" : "=v"(r) : "v"(lo), "v"(hi));
    return r;
}

__device__ __forceinline__ void gload16(const float* g, float* l) {
    __builtin_amdgcn_global_load_lds(
        (const __attribute__((address_space(1))) unsigned*)g,
        (__attribute__((address_space(3))) unsigned*)l, 16, 0, 0);
}

// ---------------------------------------------------------------------------
// ws layout (bytes):
//  qkv @ 0        : q[8192][64] row-major | KF fragment | VF fragment  bf16
//  WF  @ 3145728  : [3][32 sg][4 wc][64 lane][8] bf16 fragment layout (393,216)
//  Opart @ 3538944, MLpart @ 12713984
// ---------------------------------------------------------------------------

// ---- W -> bf16 fragment layout --------------------------------------------
__global__ __launch_bounds__(256) void wt_kernel(
    const float* __restrict__ Wq, const float* __restrict__ Wk,
    const float* __restrict__ Wv, unsigned short* __restrict__ Wt)
{
    const int f = (int)blockIdx.x * 256 + (int)threadIdx.x;  // 49152 threads
    const int n    = f & 63;
    const int rest = f >> 6;
    const int mat  = rest >> 8;
    const int kp   = (rest & 255) * 4;      // k base (multiple of 4)
    const float* W = (mat == 0) ? Wq : (mat == 1) ? Wk : Wv;
    const int sg = kp >> 5, qq = (kp >> 3) & 3, j0 = kp & 7;   // j0 in {0,4}
    const int wcg = n >> 4, c = n & 15;
    const int lanep = qq * 16 + c;
    float v0 = W[(size_t)(kp + 0) * DIM + n];
    float v1 = W[(size_t)(kp + 1) * DIM + n];
    float v2 = W[(size_t)(kp + 2) * DIM + n];
    float v3 = W[(size_t)(kp + 3) * DIM + n];
    uint2 pk;
    pk.x = cvtpk(v0, v1);
    pk.y = cvtpk(v2, v3);
    const size_t off = ((size_t)(((mat * 32 + sg) * 4 + wcg)) * 64 + lanep) * 8 + j0;
    *(uint2*)&Wt[off] = pk;
}

__device__ inline bf16x8 cvt8(float4 a, float4 b) {
    union { unsigned u[4]; bf16x8 v; } r;
    r.u[0] = cvtpk(a.x, a.y);
    r.u[1] = cvtpk(a.z, a.w);
    r.u[2] = cvtpk(b.x, b.y);
    r.u[3] = cvtpk(b.z, b.w);
    return r.v;
}

// ---- Projection: counted-vmcnt pipelined staging (T3/T4) -------------------
// 768 blocks x 512 thr. Block = 32 rows x 64 cols; BK=128, 8 K-tiles,
// 3 LDS buffers (48 KB -> 3 blocks/CU), 2-tile-deep prefetch, vmcnt never 0
// until drain. Two raw barriers per tile (read-ready / read-done).
__global__ __launch_bounds__(512) void proj_kernel(
    const float* __restrict__ x, const float* __restrict__ y, const float* __restrict__ z,
    const float* __restrict__ bq, const float* __restrict__ bk, const float* __restrict__ bv,
    const unsigned short* __restrict__ Wt, unsigned short* __restrict__ qkv)
{
    __shared__ float tile[3][32][128];   // 48 KB

    const int bid = (int)blockIdx.x;
    const int mat = bid >> 8;                 // 0=q,1=k,2=v (256 blocks each)
    const int rb  = (bid & 255) * 32;

    const int tid  = (int)threadIdx.x;
    const int lane = tid & 63;
    const int w    = tid >> 6;                // 0..7
    const int wr   = w >> 2;                  // row-tile 0..1
    const int wc   = w & 3;                   // col-tile 0..3
    const int c    = lane & 15;
    const int qq   = lane >> 4;

    const float* X  = (mat == 0) ? x  : (mat == 1) ? y  : z;
    const float* Bv = (mat == 0) ? bq : (mat == 1) ? bk : bv;
    const unsigned short* Wm = Wt + (size_t)mat * 65536;
    unsigned short* outp = qkv + (size_t)mat * (SEQ * DIM);

    f32x4 acc = (f32x4){0.f, 0.f, 0.f, 0.f};

    const int arow = wr * 16 + c;             // A-fragment LDS row
    const int swl  = arow & 7;                // read-side XOR (16B-chunk units)
    const unsigned short* Wp = Wm + (size_t)wc * 512 + (size_t)lane * 8;
    const bool swapped = (mat == 1);

    // stage tile t (k0 = t*128) into buffer nb. One instr = 2 rows (512B each):
    // lane l -> row r0+(l>>5), chunk (l&31)^(r&7). LDS dest linear (wave-uniform).
    const int sr0 = w * 4 + (lane >> 5);          // rows this lane serves (j=0)
    #define STAGE(nb, t)                                                        \
        {                                                                       \
            const int k0_ = (t) * 128;                                          \
            _Pragma("unroll")                                                   \
            for (int j = 0; j < 2; ++j) {                                       \
                const int r_ = sr0 + j * 2;                                     \
                const float* src_ = X + (size_t)(rb + r_) * EMB + k0_           \
                                      + (((lane & 31) ^ (r_ & 7)) << 2);        \
                gload16(src_, &tile[nb][w * 4 + j * 2][0]);                     \
            }                                                                   \
        }

    // compute tile t from buffer bt: 4 MFMA (sg = t*4+s)
    #define COMP(bt, t)                                                         \
        {                                                                       \
            const float* rowp = &tile[bt][arow][0];                             \
            _Pragma("unroll")                                                   \
            for (int s = 0; s < 4; ++s) {                                       \
                float4 fa = *(const float4*)(rowp + s * 32                      \
                                             + (((qq * 2)     ^ swl) << 2));    \
                float4 fb = *(const float4*)(rowp + s * 32                      \
                                             + (((qq * 2 + 1) ^ swl) << 2));    \
                bf16x8 af = cvt8(fa, fb);                                       \
                bf16x8 bfr = *(const bf16x8*)(Wp + (size_t)((t) * 4 + s) * 2048);\
                if (swapped)                                                    \
                    acc = __builtin_amdgcn_mfma_f32_16x16x32_bf16(bfr, af, acc, 0, 0, 0); \
                else                                                            \
                    acc = __builtin_amdgcn_mfma_f32_16x16x32_bf16(af, bfr, acc, 0, 0, 0); \
            }                                                                   \
        }

    STAGE(0, 0);
    STAGE(1, 1);
    STAGE(2, 2);

    #pragma unroll
    for (int t = 0; t < 8; ++t) {
        // wait for tile t's loads (newest in flight: t+1,t+2 stages = 4)
        if (t <= 5)      asm volatile("s_waitcnt vmcnt(4)" ::: "memory");
        else if (t == 6) asm volatile("s_waitcnt vmcnt(2)" ::: "memory");
        else             asm volatile("s_waitcnt vmcnt(0)" ::: "memory");
        __builtin_amdgcn_s_barrier();          // all waves' tile-t stages landed
        COMP(t % 3, t);
        if (t < 5) {
            __builtin_amdgcn_s_barrier();      // all waves done reading buf t%3
            STAGE(t % 3, t + 3);
        } else if (t < 7) {
            __builtin_amdgcn_s_barrier();
        }
    }
    #undef STAGE
    #undef COMP

    const int T = rb >> 5;
    if (mat == 0) {
        const int col = wc * 16 + c;
        const float bb = Bv[col];
        #pragma unroll
        for (int i = 0; i < 4; ++i) {
            const int row = rb + wr * 16 + qq * 4 + i;
            outp[(size_t)row * DIM + col] = f2bf(acc[i] + bb);
        }
    } else if (mat == 1) {   // KF: thread holds K^T (d = wc*16+qq*4+ii, kv = rb+wr*16+c)
        f32x4 bb4 = *(const f32x4*)&Bv[wc * 16 + qq * 4];
        const int base = (((T * 4 + wc) * 2 + (qq >> 1)) * 32 + wr * 16 + c) * 8 + (qq & 1) * 4;
        uint2 pk;
        pk.x = cvtpk(acc[0] + bb4[0], acc[1] + bb4[1]);
        pk.y = cvtpk(acc[2] + bb4[2], acc[3] + bb4[3]);
        *(uint2*)&outp[base] = pk;
    } else {                 // VF: thread holds V (kv = rb+wr*16+qq*4+ii, d = wc*16+c)
        const float bb = Bv[wc * 16 + c];
        const int base = ((((T * 2 + wr) * 2 + (wc >> 1)) * 2 + (qq >> 1)) * 32
                          + (wc & 1) * 16 + c) * 8 + (qq & 1) * 4;
        uint2 pk;
        pk.x = cvtpk(acc[0] + bb, acc[1] + bb);
        pk.y = cvtpk(acc[2] + bb, acc[3] + bb);
        *(uint2*)&outp[base] = pk;
    }
}

// ---- Flash attention: swapped-operand 32x32, KVBLK=64 pairs, defer-max -----
// 1152 blocks x 256 thr (4 waves). Unit = (qtile, 32-tile KV chunk).
// K/V read from fragment layouts: every load is base + lane*16B (coalesced).
__global__ __launch_bounds__(256, 3) void attn_kernel(
    const unsigned short* __restrict__ qkv, float* __restrict__ out,
    float* __restrict__ Opart, float* __restrict__ MLpart)
{
    const unsigned short* Q  = qkv;
    const unsigned short* KF = qkv + SEQ * DIM;
    const unsigned short* VF = qkv + 2 * SEQ * DIM;

    __shared__ float Oall[4][32][68];
    __shared__ float Ml[4][32][2];
    __shared__ float sScl[4][32];
    __shared__ float sM[32];
    __shared__ float sL[32];

    // unit id, longest-first
    const int u = 1151 - (int)blockIdx.x;
    int g;
    if (u < 32) g = 0; else if (u < 96) g = 1; else if (u < 192) g = 2;
    else if (u < 320) g = 3; else if (u < 480) g = 4; else if (u < 672) g = 5;
    else if (u < 896) g = 6; else g = 7;
    const int o_  = u - 16 * g * (g + 1);
    const int qt  = 32 * g + o_ / (g + 1);
    const int cid = o_ - (o_ / (g + 1)) * (g + 1);

    const int m0 = qt * 32;
    const int tid = (int)threadIdx.x;
    const int lane = tid & 63;
    const int w = tid >> 6;        // 0..3
    const int col = lane & 31;     // q row within tile
    const int hi = lane >> 5;

    // Q fragments (B-operand) — strided but read once per block
    bf16x8 qf[4];
    {
        const unsigned short* Qr = Q + (size_t)(m0 + col) * DIM + hi * 8;
        #pragma unroll
        for (int ks = 0; ks < 4; ++ks) qf[ks] = *(const bf16x8*)(Qr + ks * 16);
    }

    f32x16 o0, o1;
    #pragma unroll
    for (int r = 0; r < 16; ++r) { o0[r] = 0.f; o1[r] = 0.f; }
    float m_i = -1e30f, l_i = 0.f;

    const int nT = qt + 1;
    const int tb = cid * 32;
    const int te = (tb + 32 < nT) ? (tb + 32) : nT;
    const int nC = te - tb;
    const int w0 = tb + ((nC * w) >> 2);
    const int w1 = tb + ((nC * (w + 1)) >> 2);
    const int nW = w1 - w0;
    const int nP = nW >> 1;

    for (int pi = 0; pi < nP; ++pi) {
        const int t = w0 + 2 * pi;
        // ---- coalesced fragment loads: K pair + V pair ----
        const unsigned short* kb = KF + (size_t)t * 2048 + (size_t)lane * 8;
        const unsigned short* vb_ = VF + (size_t)t * 2048 + (size_t)lane * 8;
        bf16x8 kA[4], kB[4];
        #pragma unroll
        for (int ks = 0; ks < 4; ++ks) kA[ks] = *(const bf16x8*)(kb + ks * 512);
        #pragma unroll
        for (int ks = 0; ks < 4; ++ks) kB[ks] = *(const bf16x8*)(kb + 2048 + ks * 512);
        bf16x8 va[4], vbf[4];
        #pragma unroll
        for (int i = 0; i < 4; ++i) va[i]  = *(const bf16x8*)(vb_ + i * 1024);
        #pragma unroll
        for (int i = 0; i < 4; ++i) vbf[i] = *(const bf16x8*)(vb_ + 512 + i * 1024);

        // ---- dual QK chains ----
        f32x16 sa, sb;
        #pragma unroll
        for (int r = 0; r < 16; ++r) { sa[r] = 0.f; sb[r] = 0.f; }
        __builtin_amdgcn_s_setprio(1);
        #pragma unroll
        for (int ks = 0; ks < 4; ++ks) {
            sa = __builtin_amdgcn_mfma_f32_32x32x16_bf16(kA[ks], qf[ks], sa, 0, 0, 0);
            sb = __builtin_amdgcn_mfma_f32_32x32x16_bf16(kB[ks], qf[ks], sb, 0, 0, 0);
        }
        __builtin_amdgcn_s_setprio(0);

        float p0[16], p1[16];
        #pragma unroll
        for (int r = 0; r < 16; ++r) { p0[r] = sa[r] * SCL; p1[r] = sb[r] * SCL; }
        if (t + 1 == qt) {   // diagonal can only be the second tile of a pair
            #pragma unroll
            for (int r = 0; r < 16; ++r) {
                const int kvr = (r & 3) + 8 * (r >> 2) + 4 * hi;
                if (kvr > col) p1[r] = -1e30f;
            }
        }
        float tm = fmaxf(p0[0], p1[0]);
        #pragma unroll
        for (int r = 1; r < 16; ++r) tm = fmaxf(tm, fmaxf(p0[r], p1[r]));
        tm = fmaxf(tm, __shfl_xor(tm, 32));
        if (!__all(tm <= m_i + 2.0f)) {
            const float mn = fmaxf(m_i, tm);
            const float alpha = EXP2(m_i - mn);
            m_i = mn;
            l_i *= alpha;
            #pragma unroll
            for (int r = 0; r < 16; ++r) { o0[r] *= alpha; o1[r] *= alpha; }
        }
        float rs = 0.f;
        #pragma unroll
        for (int r = 0; r < 16; ++r) { p0[r] = EXP2(p0[r] - m_i); rs += p0[r]; }
        #pragma unroll
        for (int r = 0; r < 16; ++r) { p1[r] = EXP2(p1[r] - m_i); rs += p1[r]; }
        rs += __shfl_xor(rs, 32);
        l_i += rs;

        unsigned pwA[8], pwB[8];
        #pragma unroll
        for (int i = 0; i < 8; ++i) pwA[i] = cvtpk(p0[2 * i], p0[2 * i + 1]);
        #pragma unroll
        for (int i = 0; i < 8; ++i) pwB[i] = cvtpk(p1[2 * i], p1[2 * i + 1]);
        asm volatile("v_permlane32_swap_b32 %0, %1" : "+v"(pwA[0]), "+v"(pwA[2]));
        asm volatile("v_permlane32_swap_b32 %0, %1" : "+v"(pwA[1]), "+v"(pwA[3]));
        asm volatile("v_permlane32_swap_b32 %0, %1" : "+v"(pwA[4]), "+v"(pwA[6]));
        asm volatile("v_permlane32_swap_b32 %0, %1" : "+v"(pwA[5]), "+v"(pwA[7]));
        asm volatile("v_permlane32_swap_b32 %0, %1" : "+v"(pwB[0]), "+v"(pwB[2]));
        asm volatile("v_permlane32_swap_b32 %0, %1" : "+v"(pwB[1]), "+v"(pwB[3]));
        asm volatile("v_permlane32_swap_b32 %0, %1" : "+v"(pwB[4]), "+v"(pwB[6]));
        asm volatile("v_permlane32_swap_b32 %0, %1" : "+v"(pwB[5]), "+v"(pwB[7]));
        union { unsigned uu[4]; bf16x8 v; } pa0, pa1, pb0, pb1;
        pa0.uu[0] = pwA[0]; pa0.uu[1] = pwA[1]; pa0.uu[2] = pwA[2]; pa0.uu[3] = pwA[3];
        pa1.uu[0] = pwA[4]; pa1.uu[1] = pwA[5]; pa1.uu[2] = pwA[6]; pa1.uu[3] = pwA[7];
        pb0.uu[0] = pwB[0]; pb0.uu[1] = pwB[1]; pb0.uu[2] = pwB[2]; pb0.uu[3] = pwB[3];
        pb1.uu[0] = pwB[4]; pb1.uu[1] = pwB[5]; pb1.uu[2] = pwB[6]; pb1.uu[3] = pwB[7];

        __builtin_amdgcn_s_setprio(1);
        o0 = __builtin_amdgcn_mfma_f32_32x32x16_bf16(va[0],  pa0.v, o0, 0, 0, 0);
        o1 = __builtin_amdgcn_mfma_f32_32x32x16_bf16(vbf[0], pa0.v, o1, 0, 0, 0);
        o0 = __builtin_amdgcn_mfma_f32_32x32x16_bf16(va[1],  pa1.v, o0, 0, 0, 0);
        o1 = __builtin_amdgcn_mfma_f32_32x32x16_bf16(vbf[1], pa1.v, o1, 0, 0, 0);
        o0 = __builtin_amdgcn_mfma_f32_32x32x16_bf16(va[2],  pb0.v, o0, 0, 0, 0);
        o1 = __builtin_amdgcn_mfma_f32_32x32x16_bf16(vbf[2], pb0.v, o1, 0, 0, 0);
        o0 = __builtin_amdgcn_mfma_f32_32x32x16_bf16(va[3],  pb1.v, o0, 0, 0, 0);
        o1 = __builtin_amdgcn_mfma_f32_32x32x16_bf16(vbf[3], pb1.v, o1, 0, 0, 0);
        __builtin_amdgcn_s_setprio(0);
    }

    if (nW & 1) {   // tail single tile
        const int t = w1 - 1;
        const unsigned short* kb = KF + (size_t)t * 2048 + (size_t)lane * 8;
        const unsigned short* vb_ = VF + (size_t)t * 2048 + (size_t)lane * 8;
        bf16x8 kA[4];
        #pragma unroll
        for (int ks = 0; ks < 4; ++ks) kA[ks] = *(const bf16x8*)(kb + ks * 512);
        bf16x8 va0 = *(const bf16x8*)(vb_);
        bf16x8 va1 = *(const bf16x8*)(vb_ + 1024);
        bf16x8 vb0 = *(const bf16x8*)(vb_ + 512);
        bf16x8 vb1 = *(const bf16x8*)(vb_ + 1536);

        f32x16 sa;
        #pragma unroll
        for (int r = 0; r < 16; ++r) sa[r] = 0.f;
        __builtin_amdgcn_s_setprio(1);
        #pragma unroll
        for (int ks = 0; ks < 4; ++ks)
            sa = __builtin_amdgcn_mfma_f32_32x32x16_bf16(kA[ks], qf[ks], sa, 0, 0, 0);
        __builtin_amdgcn_s_setprio(0);

        float p0[16];
        #pragma unroll
        for (int r = 0; r < 16; ++r) p0[r] = sa[r] * SCL;
        if (t == qt) {
            #pragma unroll
            for (int r = 0; r < 16; ++r) {
                const int kvr = (r & 3) + 8 * (r >> 2) + 4 * hi;
                if (kvr > col) p0[r] = -1e30f;
            }
        }
        float tm = p0[0];
        #pragma unroll
        for (int r = 1; r < 16; ++r) tm = fmaxf(tm, p0[r]);
        tm = fmaxf(tm, __shfl_xor(tm, 32));
        if (!__all(tm <= m_i + 2.0f)) {
            const float mn = fmaxf(m_i, tm);
            const float alpha = EXP2(m_i - mn);
            m_i = mn;
            l_i *= alpha;
            #pragma unroll
            for (int r = 0; r < 16; ++r) { o0[r] *= alpha; o1[r] *= alpha; }
        }
        float rs = 0.f;
        #pragma unroll
        for (int r = 0; r < 16; ++r) { p0[r] = EXP2(p0[r] - m_i); rs += p0[r]; }
        rs += __shfl_xor(rs, 32);
        l_i += rs;

        unsigned pwA[8];
        #pragma unroll
        for (int i = 0; i < 8; ++i) pwA[i] = cvtpk(p0[2 * i], p0[2 * i + 1]);
        asm volatile("v_permlane32_swap_b32 %0, %1" : "+v"(pwA[0]), "+v"(pwA[2]));
        asm volatile("v_permlane32_swap_b32 %0, %1" : "+v"(pwA[1]), "+v"(pwA[3]));
        asm volatile("v_permlane32_swap_b32 %0, %1" : "+v"(pwA[4]), "+v"(pwA[6]));
        asm volatile("v_permlane32_swap_b32 %0, %1" : "+v"(pwA[5]), "+v"(pwA[7]));
        union { unsigned uu[4]; bf16x8 v; } pa0, pa1;
        pa0.uu[0] = pwA[0]; pa0.uu[1] = pwA[1]; pa0.uu[2] = pwA[2]; pa0.uu[3] = pwA[3];
        pa1.uu[0] = pwA[4]; pa1.uu[1] = pwA[5]; pa1.uu[2] = pwA[6]; pa1.uu[3] = pwA[7];

        __builtin_amdgcn_s_setprio(1);
        o0 = __builtin_amdgcn_mfma_f32_32x32x16_bf16(va0, pa0.v, o0, 0, 0, 0);
        o1 = __builtin_amdgcn_mfma_f32_32x32x16_bf16(vb0, pa0.v, o1, 0, 0, 0);
        o0 = __builtin_amdgcn_mfma_f32_32x32x16_bf16(va1, pa1.v, o0, 0, 0, 0);
        o1 = __builtin_amdgcn_mfma_f32_32x32x16_bf16(vb1, pa1.v, o1, 0, 0, 0);
        __builtin_amdgcn_s_setprio(0);
    }

    // per-wave partial -> LDS (O^T: lane col = q, regs = d)
    #pragma unroll
    for (int r = 0; r < 16; ++r) {
        const int d = (r & 3) + 8 * (r >> 2) + 4 * hi;
        Oall[w][col][d]      = o0[r];
        Oall[w][col][32 + d] = o1[r];
    }
    if (hi == 0) { Ml[w][col][0] = m_i; Ml[w][col][1] = l_i; }
    __syncthreads();

    if (tid < 32) {
        float M = Ml[0][tid][0];
        #pragma unroll
        for (int w2 = 1; w2 < 4; ++w2) M = fmaxf(M, Ml[w2][tid][0]);
        sM[tid] = M;
    }
    __syncthreads();
    if (tid < 128) {
        const int w2 = tid >> 5, r = tid & 31;
        sScl[w2][r] = EXP2(Ml[w2][r][0] - sM[r]);
    }
    __syncthreads();
    if (tid < 32) {
        float L = 0.f;
        #pragma unroll
        for (int w2 = 0; w2 < 4; ++w2) L += Ml[w2][tid][1] * sScl[w2][tid];
        sL[tid] = L;
    }
    __syncthreads();

    const int r = tid >> 3;
    const int c0 = (tid & 7) * 8;
    f32x4 a0 = (f32x4){0.f, 0.f, 0.f, 0.f};
    f32x4 a1 = (f32x4){0.f, 0.f, 0.f, 0.f};
    #pragma unroll
    for (int w2 = 0; w2 < 4; ++w2) {
        const float sc = sScl[w2][r];
        const float* Orow = &Oall[w2][r][c0];
        a0 += (*(const f32x4*)(Orow)) * sc;
        a1 += (*(const f32x4*)(Orow + 4)) * sc;
    }
    if (qt < 32) {
        const float inv = 1.f / sL[r];
        float* op = out + (size_t)(m0 + r) * DIM + c0;
        *(f32x4*)(op)     = a0 * inv;
        *(f32x4*)(op + 4) = a1 * inv;
    } else {
        const int pb = 16 * (g - 1) * (g + 2) + (qt - 32 * g) * (g + 1) + cid;
        float* op = Opart + (size_t)pb * 2048 + r * 64 + c0;
        *(f32x4*)(op)     = a0;
        *(f32x4*)(op + 4) = a1;
        if (tid < 32) {
            MLpart[(size_t)pb * 64 + tid * 2]     = sM[tid];
            MLpart[(size_t)pb * 64 + tid * 2 + 1] = sL[tid];
        }
    }
}

// ---- Fixup: merge chunk partials for qt >= 32. 224 blocks x 256 ------------
__global__ __launch_bounds__(256) void fixup_kernel(
    const float* __restrict__ Opart, const float* __restrict__ MLpart,
    float* __restrict__ out)
{
    __shared__ float sScl[8][32];
    __shared__ float sInvL[32];

    const int qt = 32 + (int)blockIdx.x;
    const int g  = qt >> 5;
    const int nc = g + 1;
    const int pb = 16 * (g - 1) * (g + 2) + (qt - 32 * g) * nc;
    const int tid = (int)threadIdx.x;

    if (tid < 32) {
        float M = -1e30f;
        for (int c2 = 0; c2 < nc; ++c2)
            M = fmaxf(M, MLpart[(size_t)(pb + c2) * 64 + tid * 2]);
        float L = 0.f;
        for (int c2 = 0; c2 < nc; ++c2) {
            const float sc = EXP2(MLpart[(size_t)(pb + c2) * 64 + tid * 2] - M);
            sScl[c2][tid] = sc;
            L += MLpart[(size_t)(pb + c2) * 64 + tid * 2 + 1] * sc;
        }
        sInvL[tid] = 1.f / L;
    }
    __syncthreads();

    const int r = tid >> 3;
    const int c0 = (tid & 7) * 8;
    f32x4 a0 = (f32x4){0.f, 0.f, 0.f, 0.f};
    f32x4 a1 = (f32x4){0.f, 0.f, 0.f, 0.f};
    for (int c2 = 0; c2 < nc; ++c2) {
        const float sc = sScl[c2][r];
        const float* Op = Opart + (size_t)(pb + c2) * 2048 + r * 64 + c0;
        a0 += (*(const f32x4*)(Op)) * sc;
        a1 += (*(const f32x4*)(Op + 4)) * sc;
    }
    const float inv = sInvL[r];
    float* op = out + (size_t)(qt * 32 + r) * DIM + c0;
    *(f32x4*)(op)     = a0 * inv;
    *(f32x4*)(op + 4) = a1 * inv;
}

extern "C" void kernel_launch(void* const* d_in, const int* in_sizes, int n_in,
                              void* d_out, int out_size, void* d_ws, size_t ws_size,
                              hipStream_t stream) {
    const float* x  = (const float*)d_in[0];
    const float* y  = (const float*)d_in[1];
    const float* z  = (const float*)d_in[2];
    const float* Wq = (const float*)d_in[3];
    const float* bq = (const float*)d_in[4];
    const float* Wk = (const float*)d_in[5];
    const float* bk = (const float*)d_in[6];
    const float* Wv = (const float*)d_in[7];
    const float* bv = (const float*)d_in[8];

    unsigned short* qkv = (unsigned short*)d_ws;
    unsigned short* Wt  = (unsigned short*)((char*)d_ws + 3145728);
    float* Opart        = (float*)((char*)d_ws + 3538944);
    float* MLpart       = (float*)((char*)d_ws + 12713984);
    float* out          = (float*)d_out;

    hipLaunchKernelGGL(wt_kernel,    dim3(192),  dim3(256), 0, stream, Wq, Wk, Wv, Wt);
    hipLaunchKernelGGL(proj_kernel,  dim3(768),  dim3(512), 0, stream, x, y, z, bq, bk, bv, Wt, qkv);
    hipLaunchKernelGGL(attn_kernel,  dim3(1152), dim3(256), 0, stream, qkv, out, Opart, MLpart);
    hipLaunchKernelGGL(fixup_kernel, dim3(224),  dim3(256), 0, stream, Opart, MLpart, out);
}